// Round 18
// baseline (276.316 us; speedup 1.0000x reference)
//
#include <hip/hip_runtime.h>
#include <hip/hip_bf16.h>

typedef unsigned short u16;
typedef __attribute__((ext_vector_type(8))) unsigned short us8;
typedef __attribute__((ext_vector_type(8))) _Float16 h8v;   // MFMA f16 A/B frag (4 VGPR)
typedef __attribute__((ext_vector_type(4))) float f32x4;    // MFMA C/D frag

#define CAP 32   // max in-degree tracked; E/N=2 (Poisson), P(deg>31) ~ 0
#define ECAP 256 // per-block gather window (64 nodes * avg deg 2 = 128)

static __device__ __forceinline__ u16 f2h(float f) {
    _Float16 h = (_Float16)f;          // RNE
    u16 r; __builtin_memcpy(&r, &h, 2); return r;
}
static __device__ __forceinline__ float h2f(u16 b) {
    _Float16 h; __builtin_memcpy(&h, &b, 2); return (float)h;
}
static __device__ __forceinline__ float sigm(float x) {
    return 1.f / (1.f + __expf(-x));
}
static __device__ __forceinline__ float tanh_f(float x) {
    return 1.f - 2.f / (__expf(2.f * x) + 1.f);
}

// ---- one-time merged prep: wf2 pack, w1/w2/w0 pack, ea->fp16, deg zero.
__global__ __launch_bounds__(256) void k_prep(
        const float* __restrict__ nn_w, const float* __restrict__ nn_b,
        const float* __restrict__ root, const float* __restrict__ w_hh,
        const float* __restrict__ w_ih, const float* __restrict__ lin0_w,
        const float* __restrict__ ea,
        u16* __restrict__ wf2, u16* __restrict__ w1, u16* __restrict__ w2,
        u16* __restrict__ w0, u16* __restrict__ ea16, int* __restrict__ deg,
        int N, int nEA) {
    int idx = blockIdx.x * 256 + threadIdx.x;
    // -- wf2: edge-GEMM A-frags. kappa = k*64+i (k-major); kappa>=1024 -> bias (z=x)
    if (idx < 34 * 4 * 512) {
        int j = idx & 7, lane = (idx >> 3) & 63;
        int rest = idx >> 9;
        int ct = rest & 3, kc = rest >> 2;
        int kappa = kc * 32 + ((lane >> 4) * 8) + j;
        int o = ct * 16 + (lane & 15);
        float v;
        if (kappa < 1024) {
            int k = kappa >> 6, i = kappa & 63;
            v = nn_w[(size_t)(i * 64 + o) * 16 + k];
        } else {
            v = nn_b[(size_t)(kappa - 1024) * 64 + o];
        }
        wf2[idx] = f2h(v);
    }
    // -- w1=[root | w_hh^T] (16 ct), w2=w_ih^T (12 ct), w0=lin0_w^T (4 ct)
    if (idx < 16384 + 12288 + 2048) {
        if (idx < 16384) {
            int j = idx & 7, lane = (idx >> 3) & 63;
            int rest = idx >> 9;          // kc*16 + ct
            int ct = rest & 15, kc = rest >> 4;
            int k = kc * 32 + ((lane >> 4) * 8) + j;
            int col = ct * 16 + (lane & 15);
            float v = (col < 64) ? root[(size_t)k * 64 + col]
                                 : w_hh[(size_t)(col - 64) * 64 + k];
            w1[idx] = f2h(v);
        } else if (idx < 16384 + 12288) {
            int i2 = idx - 16384;
            int j = i2 & 7, lane = (i2 >> 3) & 63;
            int rest = i2 >> 9;           // kc*12 + ct
            int ct = rest % 12, kc = rest / 12;
            int k = kc * 32 + ((lane >> 4) * 8) + j;
            int col = ct * 16 + (lane & 15);
            w2[i2] = f2h(w_ih[(size_t)col * 64 + k]);
        } else {
            int i3 = idx - 16384 - 12288;
            int j = i3 & 7, lane = (i3 >> 3) & 63;
            int ct = i3 >> 9;             // 0..3
            int k = ((lane >> 4) * 8) + j;
            int col = ct * 16 + (lane & 15);
            w0[i3] = f2h(lin0_w[(size_t)col * 32 + k]);
        }
    }
    if (idx < N) deg[idx] = 0;
    if (idx < nEA) ea16[idx] = f2h(ea[idx]);
}

// ---- one-time: padded in-edge table build + lin0 in one kernel (R14/R17-proven)
__global__ __launch_bounds__(256) void k_pre2(
        const int* __restrict__ ei, int* __restrict__ deg, int* __restrict__ tab,
        const float* __restrict__ x_in, const u16* __restrict__ w0,
        const float* __restrict__ lin0_b, float* __restrict__ x0,
        int N, int E) {
    int nbuild = (E + 255) / 256;
    int bid = blockIdx.x;
    int t = threadIdx.x;
    if (bid < nbuild) {
        int e = bid * 256 + t;
        if (e < E) {
            int dst = ei[E + e];
            int pos = atomicAdd(&deg[dst], 1);
            if (pos < CAP) tab[(size_t)dst * CAP + pos] = e;
        }
        return;
    }
    // lin0 (MFMA fp16): x0 = relu(x_in[N,32] @ w0 + b). 64 nodes/block.
    int b2 = bid - nbuild;
    int l = t & 63, w = t >> 6, g = l >> 4;
    int n0 = b2 * 64 + w * 16;
    int node = n0 + (l & 15);
    int nc = node < N ? node : N - 1;
    const float* xrow = x_in + (size_t)nc * 32 + g * 8;
    float4 xa = *(const float4*)(xrow);
    float4 xb = *(const float4*)(xrow + 4);
    h8v xh;
    xh[0] = (_Float16)xa.x; xh[1] = (_Float16)xa.y;
    xh[2] = (_Float16)xa.z; xh[3] = (_Float16)xa.w;
    xh[4] = (_Float16)xb.x; xh[5] = (_Float16)xb.y;
    xh[6] = (_Float16)xb.z; xh[7] = (_Float16)xb.w;
    f32x4 acc[4];
    #pragma unroll
    for (int ct = 0; ct < 4; ct++) {
        h8v wh = *(const h8v*)((const _Float16*)w0 + (ct * 64 + l) * 8);
        acc[ct] = __builtin_amdgcn_mfma_f32_16x16x32_f16(wh, xh, (f32x4)(0.f), 0, 0, 0);
    }
    if (node < N) {
        #pragma unroll
        for (int ct = 0; ct < 4; ct++) {
            int c = ct * 16 + g * 4;
            f32x4 bb = *(const f32x4*)(lin0_b + c);
            f32x4 ov;
            #pragma unroll
            for (int r = 0; r < 4; r++) ov[r] = fmaxf(acc[ct][r] + bb[r], 0.f);
            *(f32x4*)(x0 + (size_t)node * 64 + c) = ov;
        }
    }
}

// ---- AB (NNConv message, MFMA fp16, ONCE-staged LDS A-frags) — R15-proven.
__global__ __launch_bounds__(256) void k_AB(
        const float* __restrict__ x, const u16* __restrict__ ea16,
        const u16* __restrict__ wf2, const int* __restrict__ ei,
        u16* __restrict__ msg, int E) {
    __shared__ __align__(16) u16 Ab[64 * 512];   // 64 KB: kc 0..31, this ct-half
    int t = threadIdx.x, l = t & 63, w = t >> 6, g = l >> 4;
    int ctH = blockIdx.y;             // out-col half: cols ctH*32 .. ctH*32+31
    int eblk = blockIdx.x * 256 + w * 64;

    int eact[4];
    h8v xf0[4], xf1[4], eav[4][2];
    #pragma unroll
    for (int et = 0; et < 4; et++) {
        int e = eblk + et * 16 + (l & 15);
        eact[et] = e;
        int ec = e < E ? e : E - 1;
        int src = ei[ec];
        const float* xr = x + (size_t)src * 64 + g * 8;
        float4 v0 = *(const float4*)(xr);
        float4 v1 = *(const float4*)(xr + 4);
        float4 v2 = *(const float4*)(xr + 32);
        float4 v3 = *(const float4*)(xr + 36);
        h8v a, b;
        a[0] = (_Float16)v0.x; a[1] = (_Float16)v0.y;
        a[2] = (_Float16)v0.z; a[3] = (_Float16)v0.w;
        a[4] = (_Float16)v1.x; a[5] = (_Float16)v1.y;
        a[6] = (_Float16)v1.z; a[7] = (_Float16)v1.w;
        b[0] = (_Float16)v2.x; b[1] = (_Float16)v2.y;
        b[2] = (_Float16)v2.z; b[3] = (_Float16)v2.w;
        b[4] = (_Float16)v3.x; b[5] = (_Float16)v3.y;
        b[6] = (_Float16)v3.z; b[7] = (_Float16)v3.w;
        xf0[et] = a;
        xf1[et] = b;
        const _Float16* ep = (const _Float16*)ea16 + (size_t)ec * 16;
        eav[et][0] = *(const h8v*)(ep);
        eav[et][1] = *(const h8v*)(ep + 8);
    }

    const uint4* wf2u = (const uint4*)wf2;
    uint4* Abu = (uint4*)Ab;
    #pragma unroll
    for (int i = 0; i < 16; i++) {
        int j = i * 256 + t;
        int f = j >> 6, win = j & 63;        // f = kc*2+ct (local), win = lane slot
        int gf = (f >> 1) * 4 + ctH * 2 + (f & 1);
        Abu[j] = wf2u[(size_t)gf * 64 + win];
    }
    __syncthreads();   // the ONLY barrier

    f32x4 acc[4][2];
    #pragma unroll
    for (int et = 0; et < 4; et++)
        #pragma unroll
        for (int ct = 0; ct < 2; ct++) acc[et][ct] = (f32x4)(0.f);

    const _Float16* AbH = (const _Float16*)Ab;
    const _Float16* wfh = (const _Float16*)wf2;

    #pragma unroll
    for (int p = 0; p < 8; p++) {
        #pragma unroll
        for (int kcl = 0; kcl < 4; kcl++) {
            int kc = p * 4 + kcl;
            h8v af[2];
            #pragma unroll
            for (int ct = 0; ct < 2; ct++)
                af[ct] = *(const h8v*)(AbH + (size_t)(kc * 2 + ct) * 512 + l * 8);
            const int k = 2 * p + (kcl >> 1);   // compile-time after unroll
            #pragma unroll
            for (int et = 0; et < 4; et++) {
                _Float16 s = eav[et][k >> 3][k & 7];
                h8v es = {s, s, s, s, s, s, s, s};
                h8v zf = es * ((kcl & 1) ? xf1[et] : xf0[et]);
                #pragma unroll
                for (int ct = 0; ct < 2; ct++)
                    acc[et][ct] = __builtin_amdgcn_mfma_f32_16x16x32_f16(af[ct], zf, acc[et][ct], 0, 0, 0);
            }
        }
    }
    // bias block: kc = 32,33 ; z = x fragment; A-frags direct from L2 (hot)
    #pragma unroll
    for (int kcl = 0; kcl < 2; kcl++) {
        int kc = 32 + kcl;
        h8v af[2];
        #pragma unroll
        for (int ct = 0; ct < 2; ct++)
            af[ct] = *(const h8v*)(wfh + (size_t)(kc * 4 + ctH * 2 + ct) * 512 + l * 8);
        #pragma unroll
        for (int et = 0; et < 4; et++) {
            h8v zf = (kcl & 1) ? xf1[et] : xf0[et];
            #pragma unroll
            for (int ct = 0; ct < 2; ct++)
                acc[et][ct] = __builtin_amdgcn_mfma_f32_16x16x32_f16(af[ct], zf, acc[et][ct], 0, 0, 0);
        }
    }

    #pragma unroll
    for (int et = 0; et < 4; et++) {
        int e = eact[et];
        if (e < E) {
            u16* mr = msg + (size_t)e * 64 + g * 4;
            #pragma unroll
            for (int ct = 0; ct < 2; ct++) {
                ushort4 pk;
                pk.x = f2h(acc[et][ct][0]);
                pk.y = f2h(acc[et][ct][1]);
                pk.z = f2h(acc[et][ct][2]);
                pk.w = f2h(acc[et][ct][3]);
                *(ushort4*)(mr + (ctH * 2 + ct) * 16) = pk;
            }
        }
    }
}

// ---- C (fused gather + C1 + C2, MFMA fp16):
// NEW gather: edge-slot-parallel with LDS fp32 atomic accumulation.
// Old node-parallel gather ran max-deg(wave) ~6 divergent passes of scattered
// dependent loads; this runs exact-work uniform passes over (slot, 8-col)
// tasks. Scan/fill machinery is R14-proven. LDS ~36.6 KB -> still 4 blocks/CU
// (VGPR-capped), unlike R16's 50 KB w1-staging cliff.
__global__ __launch_bounds__(256) void k_C(
        const float* __restrict__ x, const u16* __restrict__ msg,
        const int* __restrict__ deg, const int* __restrict__ tab,
        const u16* __restrict__ w1, const u16* __restrict__ w2,
        const float* __restrict__ conv_b, const float* __restrict__ b_hh,
        const float* __restrict__ b_ih, float* __restrict__ hout, int N) {
    __shared__ float mld[4][16][68];
    __shared__ float aggs[64][68];     // stride 68: 16B-aligned rows, 2-way max conflict
    __shared__ int els[ECAP];
    __shared__ short nds[ECAP];
    __shared__ int offs[65];
    int t = threadIdx.x, l = t & 63, w = t >> 6, g = l >> 4;
    int n0 = blockIdx.x * 64;
    int nb = w * 16 + (l & 15);
    int node = n0 + nb;
    int nc = node < N ? node : N - 1;
    const float* xrow = x + (size_t)nc * 64 + g * 8;
    const _Float16* w1h = (const _Float16*)w1;
    const _Float16* w2h = (const _Float16*)w2;

    // x fragments (B operand)
    h8v xh[2];
    #pragma unroll
    for (int kc = 0; kc < 2; kc++) {
        f32x4 a = *(const f32x4*)(xrow + kc * 32);
        f32x4 b = *(const f32x4*)(xrow + kc * 32 + 4);
        #pragma unroll
        for (int j = 0; j < 8; j++) xh[kc][j] = (_Float16)(j < 4 ? a[j] : b[j - 4]);
    }

    // scan (wave 0) + aggs zero (all waves)
    if (w == 0) {
        int nd = n0 + l;
        int d = 0;
        if (nd < N) { d = deg[nd]; if (d > CAP) d = CAP; }
        int s = d;
        #pragma unroll
        for (int o = 1; o < 64; o <<= 1) {
            int v = __shfl_up(s, o, 64);
            if (l >= o) s += v;
        }
        offs[l + 1] = s;
        if (l == 0) offs[0] = 0;
    }
    {
        float* af = &aggs[0][0];
        for (int i = t; i < 64 * 68; i += 256) af[i] = 0.f;
    }
    __syncthreads();
    int T_e = offs[64];

    // edge-slot-parallel gather (windows; nearly always one)
    for (int base = 0; base < T_e; base += ECAP) {
        int cnt = T_e - base; if (cnt > ECAP) cnt = ECAP;
        if (w == 0) {
            int nd = n0 + l;
            int d = 0;
            if (nd < N) { d = deg[nd]; if (d > CAP) d = CAP; }
            int o = offs[l];
            const int* tr = tab + (size_t)(nd < N ? nd : 0) * CAP;
            for (int j = 0; j < d; j++) {
                int s = o + j - base;
                if (s >= 0 && s < ECAP) { els[s] = tr[j]; nds[s] = (short)l; }
            }
        }
        __syncthreads();
        // tasks: (slot, 8-col group); uniform trip count, exact work
        for (int task = t; task < cnt * 8; task += 256) {
            int s = task >> 3, cq = task & 7;
            int eid = els[s];
            int n = nds[s];
            us8 v = *(const us8*)(msg + (size_t)eid * 64 + cq * 8);
            #pragma unroll
            for (int i = 0; i < 8; i++)
                atomicAdd(&aggs[n][cq * 8 + i], h2f(v[i]));
        }
        __syncthreads();
    }

    // own node's sums from LDS
    f32x4 avs[4];
    #pragma unroll
    for (int ct = 0; ct < 4; ct++)
        avs[ct] = *(const f32x4*)(&aggs[nb][ct * 16 + g * 4]);

    // phase1: A-frags direct from L2 (28 KB shared chip-wide, L2-hot)
    f32x4 acc1[16];
    #pragma unroll
    for (int ct = 0; ct < 16; ct++) acc1[ct] = (f32x4)(0.f);
    #pragma unroll
    for (int kc = 0; kc < 2; kc++) {
        #pragma unroll
        for (int ct = 0; ct < 16; ct++) {
            h8v wh = *(const h8v*)(w1h + (size_t)(kc * 16 + ct) * 512 + l * 8);
            acc1[ct] = __builtin_amdgcn_mfma_f32_16x16x32_f16(wh, xh[kc], acc1[ct], 0, 0, 0);
        }
    }

    // epilogue 1: m -> LDS (16x64 lane transpose); gh = acc1[4..15]+b_hh
    #pragma unroll
    for (int ct = 0; ct < 4; ct++) {
        int c = ct * 16 + g * 4;
        f32x4 cb = *(const f32x4*)(conv_b + c);
        f32x4 mv;
        #pragma unroll
        for (int r = 0; r < 4; r++) mv[r] = fmaxf(acc1[ct][r] + avs[ct][r] + cb[r], 0.f);
        *(f32x4*)(&mld[w][l & 15][c]) = mv;
    }
    #pragma unroll
    for (int ct = 4; ct < 16; ct++) {
        int c = (ct - 4) * 16 + g * 4;
        f32x4 bh = *(const f32x4*)(b_hh + c);
        #pragma unroll
        for (int r = 0; r < 4; r++) acc1[ct][r] += bh[r];
    }
    __syncthreads();   // fence for the cross-lane LDS transpose (R9 lesson)

    h8v mh[2];
    #pragma unroll
    for (int kc = 0; kc < 2; kc++) {
        const float* mr = &mld[w][l & 15][kc * 32 + g * 8];
        f32x4 a = *(const f32x4*)(mr);
        f32x4 b = *(const f32x4*)(mr + 4);
        #pragma unroll
        for (int j = 0; j < 8; j++) mh[kc][j] = (_Float16)(j < 4 ? a[j] : b[j - 4]);
    }

    // phase2
    f32x4 acc2[12];
    #pragma unroll
    for (int ct = 0; ct < 12; ct++) acc2[ct] = (f32x4)(0.f);
    #pragma unroll
    for (int kc = 0; kc < 2; kc++) {
        #pragma unroll
        for (int ct = 0; ct < 12; ct++) {
            h8v wh = *(const h8v*)(w2h + (size_t)(kc * 12 + ct) * 512 + l * 8);
            acc2[ct] = __builtin_amdgcn_mfma_f32_16x16x32_f16(wh, mh[kc], acc2[ct], 0, 0, 0);
        }
    }

    // epilogue 2: gates (all lane-local)
    #pragma unroll
    for (int q = 0; q < 4; q++) {
        int c = q * 16 + g * 4;
        f32x4 bir = *(const f32x4*)(b_ih + c);
        f32x4 biz = *(const f32x4*)(b_ih + 64 + c);
        f32x4 bin = *(const f32x4*)(b_ih + 128 + c);
        f32x4 hv = (f32x4)(0.f);
        if (node < N) hv = *(const f32x4*)(x + (size_t)node * 64 + c);
        f32x4 outv;
        #pragma unroll
        for (int r = 0; r < 4; r++) {
            float rr = sigm(acc2[q][r] + bir[r] + acc1[4 + q][r]);
            float zz = sigm(acc2[4 + q][r] + biz[r] + acc1[8 + q][r]);
            float nt = tanh_f(acc2[8 + q][r] + bin[r] + rr * acc1[12 + q][r]);
            outv[r] = (1.f - zz) * nt + zz * hv[r];
        }
        if (node < N) *(f32x4*)(hout + (size_t)node * 64 + c) = outv;
    }
}

extern "C" void kernel_launch(void* const* d_in, const int* in_sizes, int n_in,
                              void* d_out, int out_size, void* d_ws, size_t ws_size,
                              hipStream_t stream) {
    const float* x_in   = (const float*)d_in[0];
    const int*   ei     = (const int*)d_in[1];
    const float* ea     = (const float*)d_in[2];
    const float* lin0_w = (const float*)d_in[3];
    const float* lin0_b = (const float*)d_in[4];
    const float* nn_w   = (const float*)d_in[5];
    const float* nn_b   = (const float*)d_in[6];
    const float* root   = (const float*)d_in[7];
    const float* conv_b = (const float*)d_in[8];
    const float* w_ih   = (const float*)d_in[9];
    const float* w_hh   = (const float*)d_in[10];
    const float* b_ih   = (const float*)d_in[11];
    const float* b_hh   = (const float*)d_in[12];

    int N = in_sizes[0] / 32;
    int E = in_sizes[1] / 2;

    char* ws = (char*)d_ws;
    size_t off = 0;
    auto alloc = [&](size_t bytes) { char* p = ws + off; off += (bytes + 255) & ~(size_t)255; return p; };
    float* xbuf   = (float*)alloc((size_t)N * 64 * 4);
    u16*   msg    = (u16*)alloc((size_t)E * 64 * 2);
    u16*   wf2    = (u16*)alloc((size_t)34 * 4 * 512 * 2);
    u16*   ea16   = (u16*)alloc((size_t)E * 16 * 2);
    u16*   w1     = (u16*)alloc(16384 * 2);
    u16*   w2     = (u16*)alloc(12288 * 2);
    u16*   w0     = (u16*)alloc(2048 * 2);
    int*   deg    = (int*)alloc((size_t)N * 4);
    int*   tab    = (int*)alloc((size_t)N * CAP * 4);
    (void)ws_size;

    int nEA = E * 16;
    int nbuild = (E + 255) / 256;
    int ntile  = (N + 63) / 64;

    hipLaunchKernelGGL(k_prep, dim3((nEA + 255) / 256), dim3(256), 0, stream,
                       nn_w, nn_b, root, w_hh, w_ih, lin0_w, ea,
                       wf2, w1, w2, w0, ea16, deg, N, nEA);
    hipLaunchKernelGGL(k_pre2, dim3(nbuild + ntile), dim3(256), 0, stream,
                       ei, deg, tab, x_in, w0, lin0_b, xbuf, N, E);

    for (int it = 0; it < 3; it++) {
        hipLaunchKernelGGL(k_AB, dim3((E + 255) / 256, 2), dim3(256), 0, stream,
                           xbuf, ea16, wf2, ei, msg, E);
        float* hout = (it == 2) ? (float*)d_out : xbuf;
        hipLaunchKernelGGL(k_C, dim3(ntile), dim3(256), 0, stream, xbuf, msg,
                           deg, tab, w1, w2, conv_b, b_hh, b_ih, hout, N);
    }
}

// Round 19
// 184.172 us; speedup vs baseline: 1.5003x; 1.5003x over previous
//
#include <hip/hip_runtime.h>
#include <hip/hip_bf16.h>

typedef unsigned short u16;
typedef __attribute__((ext_vector_type(8))) _Float16 h8v;   // MFMA f16 A/B frag (4 VGPR)
typedef __attribute__((ext_vector_type(4))) float f32x4;    // MFMA C/D frag

#define CAP 32  // max in-degree tracked; E/N=2 (Poisson), P(deg>31) ~ 0

static __device__ __forceinline__ u16 f2h(float f) {
    _Float16 h = (_Float16)f;          // RNE
    u16 r; __builtin_memcpy(&r, &h, 2); return r;
}
static __device__ __forceinline__ float h2f(u16 b) {
    _Float16 h; __builtin_memcpy(&h, &b, 2); return (float)h;
}
static __device__ __forceinline__ float sigm(float x) {
    return 1.f / (1.f + __expf(-x));
}
static __device__ __forceinline__ float tanh_f(float x) {
    return 1.f - 2.f / (__expf(2.f * x) + 1.f);
}

// ---- one-time merged prep: wf2 pack, w1/w2/w0 pack, ea->fp16, deg zero.
__global__ __launch_bounds__(256) void k_prep(
        const float* __restrict__ nn_w, const float* __restrict__ nn_b,
        const float* __restrict__ root, const float* __restrict__ w_hh,
        const float* __restrict__ w_ih, const float* __restrict__ lin0_w,
        const float* __restrict__ ea,
        u16* __restrict__ wf2, u16* __restrict__ w1, u16* __restrict__ w2,
        u16* __restrict__ w0, u16* __restrict__ ea16, int* __restrict__ deg,
        int N, int nEA) {
    int idx = blockIdx.x * 256 + threadIdx.x;
    // -- wf2: edge-GEMM A-frags. kappa = k*64+i (k-major); kappa>=1024 -> bias (z=x)
    if (idx < 34 * 4 * 512) {
        int j = idx & 7, lane = (idx >> 3) & 63;
        int rest = idx >> 9;
        int ct = rest & 3, kc = rest >> 2;
        int kappa = kc * 32 + ((lane >> 4) * 8) + j;
        int o = ct * 16 + (lane & 15);
        float v;
        if (kappa < 1024) {
            int k = kappa >> 6, i = kappa & 63;
            v = nn_w[(size_t)(i * 64 + o) * 16 + k];
        } else {
            v = nn_b[(size_t)(kappa - 1024) * 64 + o];
        }
        wf2[idx] = f2h(v);
    }
    // -- w1=[root | w_hh^T] (16 ct), w2=w_ih^T (12 ct), w0=lin0_w^T (4 ct)
    if (idx < 16384 + 12288 + 2048) {
        if (idx < 16384) {
            int j = idx & 7, lane = (idx >> 3) & 63;
            int rest = idx >> 9;          // kc*16 + ct
            int ct = rest & 15, kc = rest >> 4;
            int k = kc * 32 + ((lane >> 4) * 8) + j;
            int col = ct * 16 + (lane & 15);
            float v = (col < 64) ? root[(size_t)k * 64 + col]
                                 : w_hh[(size_t)(col - 64) * 64 + k];
            w1[idx] = f2h(v);
        } else if (idx < 16384 + 12288) {
            int i2 = idx - 16384;
            int j = i2 & 7, lane = (i2 >> 3) & 63;
            int rest = i2 >> 9;           // kc*12 + ct
            int ct = rest % 12, kc = rest / 12;
            int k = kc * 32 + ((lane >> 4) * 8) + j;
            int col = ct * 16 + (lane & 15);
            w2[i2] = f2h(w_ih[(size_t)col * 64 + k]);
        } else {
            int i3 = idx - 16384 - 12288;
            int j = i3 & 7, lane = (i3 >> 3) & 63;
            int ct = i3 >> 9;             // 0..3
            int k = ((lane >> 4) * 8) + j;
            int col = ct * 16 + (lane & 15);
            w0[i3] = f2h(lin0_w[(size_t)col * 32 + k]);
        }
    }
    if (idx < N) deg[idx] = 0;
    if (idx < nEA) ea16[idx] = f2h(ea[idx]);
}

// ---- one-time: padded in-edge table build + lin0 in one kernel (R14/R17-proven)
__global__ __launch_bounds__(256) void k_pre2(
        const int* __restrict__ ei, int* __restrict__ deg, int* __restrict__ tab,
        const float* __restrict__ x_in, const u16* __restrict__ w0,
        const float* __restrict__ lin0_b, float* __restrict__ x0,
        int N, int E) {
    int nbuild = (E + 255) / 256;
    int bid = blockIdx.x;
    int t = threadIdx.x;
    if (bid < nbuild) {
        int e = bid * 256 + t;
        if (e < E) {
            int dst = ei[E + e];
            int pos = atomicAdd(&deg[dst], 1);
            if (pos < CAP) tab[(size_t)dst * CAP + pos] = e;
        }
        return;
    }
    // lin0 (MFMA fp16): x0 = relu(x_in[N,32] @ w0 + b). 64 nodes/block.
    int b2 = bid - nbuild;
    int l = t & 63, w = t >> 6, g = l >> 4;
    int n0 = b2 * 64 + w * 16;
    int node = n0 + (l & 15);
    int nc = node < N ? node : N - 1;
    const float* xrow = x_in + (size_t)nc * 32 + g * 8;
    float4 xa = *(const float4*)(xrow);
    float4 xb = *(const float4*)(xrow + 4);
    h8v xh;
    xh[0] = (_Float16)xa.x; xh[1] = (_Float16)xa.y;
    xh[2] = (_Float16)xa.z; xh[3] = (_Float16)xa.w;
    xh[4] = (_Float16)xb.x; xh[5] = (_Float16)xb.y;
    xh[6] = (_Float16)xb.z; xh[7] = (_Float16)xb.w;
    f32x4 acc[4];
    #pragma unroll
    for (int ct = 0; ct < 4; ct++) {
        h8v wh = *(const h8v*)((const _Float16*)w0 + (ct * 64 + l) * 8);
        acc[ct] = __builtin_amdgcn_mfma_f32_16x16x32_f16(wh, xh, (f32x4)(0.f), 0, 0, 0);
    }
    if (node < N) {
        #pragma unroll
        for (int ct = 0; ct < 4; ct++) {
            int c = ct * 16 + g * 4;
            f32x4 bb = *(const f32x4*)(lin0_b + c);
            f32x4 ov;
            #pragma unroll
            for (int r = 0; r < 4; r++) ov[r] = fmaxf(acc[ct][r] + bb[r], 0.f);
            *(f32x4*)(x0 + (size_t)node * 64 + c) = ov;
        }
    }
}

// ---- AB (NNConv message, MFMA fp16, ONCE-staged LDS A-frags) — R15-proven.
__global__ __launch_bounds__(256) void k_AB(
        const float* __restrict__ x, const u16* __restrict__ ea16,
        const u16* __restrict__ wf2, const int* __restrict__ ei,
        u16* __restrict__ msg, int E) {
    __shared__ __align__(16) u16 Ab[64 * 512];   // 64 KB: kc 0..31, this ct-half
    int t = threadIdx.x, l = t & 63, w = t >> 6, g = l >> 4;
    int ctH = blockIdx.y;             // out-col half: cols ctH*32 .. ctH*32+31
    int eblk = blockIdx.x * 256 + w * 64;

    int eact[4];
    h8v xf0[4], xf1[4], eav[4][2];
    #pragma unroll
    for (int et = 0; et < 4; et++) {
        int e = eblk + et * 16 + (l & 15);
        eact[et] = e;
        int ec = e < E ? e : E - 1;
        int src = ei[ec];
        const float* xr = x + (size_t)src * 64 + g * 8;
        float4 v0 = *(const float4*)(xr);
        float4 v1 = *(const float4*)(xr + 4);
        float4 v2 = *(const float4*)(xr + 32);
        float4 v3 = *(const float4*)(xr + 36);
        h8v a, b;
        a[0] = (_Float16)v0.x; a[1] = (_Float16)v0.y;
        a[2] = (_Float16)v0.z; a[3] = (_Float16)v0.w;
        a[4] = (_Float16)v1.x; a[5] = (_Float16)v1.y;
        a[6] = (_Float16)v1.z; a[7] = (_Float16)v1.w;
        b[0] = (_Float16)v2.x; b[1] = (_Float16)v2.y;
        b[2] = (_Float16)v2.z; b[3] = (_Float16)v2.w;
        b[4] = (_Float16)v3.x; b[5] = (_Float16)v3.y;
        b[6] = (_Float16)v3.z; b[7] = (_Float16)v3.w;
        xf0[et] = a;
        xf1[et] = b;
        const _Float16* ep = (const _Float16*)ea16 + (size_t)ec * 16;
        eav[et][0] = *(const h8v*)(ep);
        eav[et][1] = *(const h8v*)(ep + 8);
    }

    const uint4* wf2u = (const uint4*)wf2;
    uint4* Abu = (uint4*)Ab;
    #pragma unroll
    for (int i = 0; i < 16; i++) {
        int j = i * 256 + t;
        int f = j >> 6, win = j & 63;        // f = kc*2+ct (local), win = lane slot
        int gf = (f >> 1) * 4 + ctH * 2 + (f & 1);
        Abu[j] = wf2u[(size_t)gf * 64 + win];
    }
    __syncthreads();   // the ONLY barrier

    f32x4 acc[4][2];
    #pragma unroll
    for (int et = 0; et < 4; et++)
        #pragma unroll
        for (int ct = 0; ct < 2; ct++) acc[et][ct] = (f32x4)(0.f);

    const _Float16* AbH = (const _Float16*)Ab;
    const _Float16* wfh = (const _Float16*)wf2;

    #pragma unroll
    for (int p = 0; p < 8; p++) {
        #pragma unroll
        for (int kcl = 0; kcl < 4; kcl++) {
            int kc = p * 4 + kcl;
            h8v af[2];
            #pragma unroll
            for (int ct = 0; ct < 2; ct++)
                af[ct] = *(const h8v*)(AbH + (size_t)(kc * 2 + ct) * 512 + l * 8);
            const int k = 2 * p + (kcl >> 1);   // compile-time after unroll
            #pragma unroll
            for (int et = 0; et < 4; et++) {
                _Float16 s = eav[et][k >> 3][k & 7];
                h8v es = {s, s, s, s, s, s, s, s};
                h8v zf = es * ((kcl & 1) ? xf1[et] : xf0[et]);
                #pragma unroll
                for (int ct = 0; ct < 2; ct++)
                    acc[et][ct] = __builtin_amdgcn_mfma_f32_16x16x32_f16(af[ct], zf, acc[et][ct], 0, 0, 0);
            }
        }
    }
    // bias block: kc = 32,33 ; z = x fragment; A-frags direct from L2 (hot)
    #pragma unroll
    for (int kcl = 0; kcl < 2; kcl++) {
        int kc = 32 + kcl;
        h8v af[2];
        #pragma unroll
        for (int ct = 0; ct < 2; ct++)
            af[ct] = *(const h8v*)(wfh + (size_t)(kc * 4 + ctH * 2 + ct) * 512 + l * 8);
        #pragma unroll
        for (int et = 0; et < 4; et++) {
            h8v zf = (kcl & 1) ? xf1[et] : xf0[et];
            #pragma unroll
            for (int ct = 0; ct < 2; ct++)
                acc[et][ct] = __builtin_amdgcn_mfma_f32_16x16x32_f16(af[ct], zf, acc[et][ct], 0, 0, 0);
        }
    }

    #pragma unroll
    for (int et = 0; et < 4; et++) {
        int e = eact[et];
        if (e < E) {
            u16* mr = msg + (size_t)e * 64 + g * 4;
            #pragma unroll
            for (int ct = 0; ct < 2; ct++) {
                ushort4 pk;
                pk.x = f2h(acc[et][ct][0]);
                pk.y = f2h(acc[et][ct][1]);
                pk.z = f2h(acc[et][ct][2]);
                pk.w = f2h(acc[et][ct][3]);
                *(ushort4*)(mr + (ctH * 2 + ct) * 16) = pk;
            }
        }
    }
}

// ---- C (fused gather + C1 + C2, MFMA fp16, col-half split + 2-tile reuse):
// Wave = (colHalf h, tilePair tp): handles output cols h*32..h*32+31 of
// node tiles 2tp, 2tp+1. Each w-fragment is loaded ONCE and feeds TWO MFMAs
// (one per tile) -> per-wave L2 loads halve vs R17 (28 loads : 56 MFMAs).
// Gate columns for half h need exactly the ct sets below -> gates lane-local.
// m col-halves are exchanged through mld across the existing barrier.
// LDS unchanged 17.4 KB (no R16 cliff); VGPR ~190 (bounded, no R14 blowup).
__global__ __launch_bounds__(256) void k_C(
        const float* __restrict__ x, const u16* __restrict__ msg,
        const int* __restrict__ deg, const int* __restrict__ tab,
        const u16* __restrict__ w1, const u16* __restrict__ w2,
        const float* __restrict__ conv_b, const float* __restrict__ b_hh,
        const float* __restrict__ b_ih, float* __restrict__ hout, int N) {
    __shared__ float mld[4][16][68];
    int t = threadIdx.x, l = t & 63, w = t >> 6, g = l >> 4;
    int h = w & 1;                 // col half
    int tp = w >> 1;               // tile pair: tiles 2tp, 2tp+1
    int n0 = blockIdx.x * 64;
    const _Float16* w1h = (const _Float16*)w1;
    const _Float16* w2h = (const _Float16*)w2;
    int h2 = h * 2;

    int tile[2], node[2];
    h8v xh[2][2];
    #pragma unroll
    for (int tt = 0; tt < 2; tt++) {
        tile[tt] = 2 * tp + tt;
        node[tt] = n0 + tile[tt] * 16 + (l & 15);
        int nc = node[tt] < N ? node[tt] : N - 1;
        const float* xrow = x + (size_t)nc * 64 + g * 8;
        #pragma unroll
        for (int kc = 0; kc < 2; kc++) {
            f32x4 a = *(const f32x4*)(xrow + kc * 32);
            f32x4 b = *(const f32x4*)(xrow + kc * 32 + 4);
            #pragma unroll
            for (int j = 0; j < 8; j++)
                xh[tt][kc][j] = (_Float16)(j < 4 ? a[j] : b[j - 4]);
        }
    }

    // gather in-edge msg sums for this wave's col-half (2 cts per tile)
    f32x4 avs[2][2];
    #pragma unroll
    for (int tt = 0; tt < 2; tt++) {
        avs[tt][0] = (f32x4)(0.f);
        avs[tt][1] = (f32x4)(0.f);
        if (node[tt] < N) {
            int dg = deg[node[tt]];
            dg = dg < CAP ? dg : CAP;
            const int* tr = tab + (size_t)node[tt] * CAP;
            for (int j = 0; j < dg; j++) {
                int eid = tr[j];
                const u16* mr = msg + (size_t)eid * 64 + g * 4;
                #pragma unroll
                for (int ct = 0; ct < 2; ct++) {
                    ushort4 mv = *(const ushort4*)(mr + (h2 + ct) * 16);
                    avs[tt][ct][0] += h2f(mv.x);
                    avs[tt][ct][1] += h2f(mv.y);
                    avs[tt][ct][2] += h2f(mv.z);
                    avs[tt][ct][3] += h2f(mv.w);
                }
            }
        }
    }

    // phase1: w1 cts {h2,h2+1, 4+h2,5+h2, 8+h2,9+h2, 12+h2,13+h2}
    // acc1[tt][0..1]=m, [2..3]=gh_r, [4..5]=gh_z, [6..7]=gh_n
    f32x4 acc1[2][8];
    #pragma unroll
    for (int tt = 0; tt < 2; tt++)
        #pragma unroll
        for (int i = 0; i < 8; i++) acc1[tt][i] = (f32x4)(0.f);
    #pragma unroll
    for (int kc = 0; kc < 2; kc++) {
        #pragma unroll
        for (int i = 0; i < 8; i++) {
            int ct = (i >> 1) * 4 + h2 + (i & 1);   // {h2,h2+1,4+h2,...}
            h8v wh = *(const h8v*)(w1h + (size_t)(kc * 16 + ct) * 512 + l * 8);
            #pragma unroll
            for (int tt = 0; tt < 2; tt++)
                acc1[tt][i] = __builtin_amdgcn_mfma_f32_16x16x32_f16(wh, xh[tt][kc], acc1[tt][i], 0, 0, 0);
        }
    }

    // epilogue 1: m (this col-half) -> mld ; gh += b_hh
    #pragma unroll
    for (int tt = 0; tt < 2; tt++) {
        #pragma unroll
        for (int i = 0; i < 2; i++) {
            int c = (h2 + i) * 16 + g * 4;
            f32x4 cb = *(const f32x4*)(conv_b + c);
            f32x4 mv;
            #pragma unroll
            for (int r = 0; r < 4; r++)
                mv[r] = fmaxf(acc1[tt][i][r] + avs[tt][i][r] + cb[r], 0.f);
            *(f32x4*)(&mld[tile[tt]][l & 15][c]) = mv;
        }
        #pragma unroll
        for (int i = 2; i < 8; i++) {
            int c = ((i - 2) >> 1) * 64 + (h2 + (i & 1)) * 16 + g * 4;  // gh col
            f32x4 bh = *(const f32x4*)(b_hh + c);
            #pragma unroll
            for (int r = 0; r < 4; r++) acc1[tt][i][r] += bh[r];
        }
    }
    __syncthreads();   // cross-wave m-half exchange (R9 lesson: fence required)

    h8v mh[2][2];
    #pragma unroll
    for (int tt = 0; tt < 2; tt++) {
        #pragma unroll
        for (int kc = 0; kc < 2; kc++) {
            const float* mr = &mld[tile[tt]][l & 15][kc * 32 + g * 8];
            f32x4 a = *(const f32x4*)(mr);
            f32x4 b = *(const f32x4*)(mr + 4);
            #pragma unroll
            for (int j = 0; j < 8; j++)
                mh[tt][kc][j] = (_Float16)(j < 4 ? a[j] : b[j - 4]);
        }
    }

    // phase2: w2 cts {h2,h2+1, 4+h2,5+h2, 8+h2,9+h2}
    // acc2[tt][0..1]=gi_r, [2..3]=gi_z, [4..5]=gi_n
    f32x4 acc2[2][6];
    #pragma unroll
    for (int tt = 0; tt < 2; tt++)
        #pragma unroll
        for (int i = 0; i < 6; i++) acc2[tt][i] = (f32x4)(0.f);
    #pragma unroll
    for (int kc = 0; kc < 2; kc++) {
        #pragma unroll
        for (int i = 0; i < 6; i++) {
            int ct = (i >> 1) * 4 + h2 + (i & 1);
            h8v wh = *(const h8v*)(w2h + (size_t)(kc * 12 + ct) * 512 + l * 8);
            #pragma unroll
            for (int tt = 0; tt < 2; tt++)
                acc2[tt][i] = __builtin_amdgcn_mfma_f32_16x16x32_f16(wh, mh[tt][kc], acc2[tt][i], 0, 0, 0);
        }
    }

    // gates: q in 0..1 -> output col c = (h2+q)*16 + g*4 (lane-local)
    #pragma unroll
    for (int tt = 0; tt < 2; tt++) {
        #pragma unroll
        for (int q = 0; q < 2; q++) {
            int c = (h2 + q) * 16 + g * 4;
            f32x4 bir = *(const f32x4*)(b_ih + c);
            f32x4 biz = *(const f32x4*)(b_ih + 64 + c);
            f32x4 bin = *(const f32x4*)(b_ih + 128 + c);
            f32x4 hv = (f32x4)(0.f);
            if (node[tt] < N) hv = *(const f32x4*)(x + (size_t)node[tt] * 64 + c);
            f32x4 outv;
            #pragma unroll
            for (int r = 0; r < 4; r++) {
                float rr = sigm(acc2[tt][q][r] + bir[r] + acc1[tt][2 + q][r]);
                float zz = sigm(acc2[tt][2 + q][r] + biz[r] + acc1[tt][4 + q][r]);
                float nt = tanh_f(acc2[tt][4 + q][r] + bin[r] + rr * acc1[tt][6 + q][r]);
                outv[r] = (1.f - zz) * nt + zz * hv[r];
            }
            if (node[tt] < N) *(f32x4*)(hout + (size_t)node[tt] * 64 + c) = outv;
        }
    }
}

extern "C" void kernel_launch(void* const* d_in, const int* in_sizes, int n_in,
                              void* d_out, int out_size, void* d_ws, size_t ws_size,
                              hipStream_t stream) {
    const float* x_in   = (const float*)d_in[0];
    const int*   ei     = (const int*)d_in[1];
    const float* ea     = (const float*)d_in[2];
    const float* lin0_w = (const float*)d_in[3];
    const float* lin0_b = (const float*)d_in[4];
    const float* nn_w   = (const float*)d_in[5];
    const float* nn_b   = (const float*)d_in[6];
    const float* root   = (const float*)d_in[7];
    const float* conv_b = (const float*)d_in[8];
    const float* w_ih   = (const float*)d_in[9];
    const float* w_hh   = (const float*)d_in[10];
    const float* b_ih   = (const float*)d_in[11];
    const float* b_hh   = (const float*)d_in[12];

    int N = in_sizes[0] / 32;
    int E = in_sizes[1] / 2;

    char* ws = (char*)d_ws;
    size_t off = 0;
    auto alloc = [&](size_t bytes) { char* p = ws + off; off += (bytes + 255) & ~(size_t)255; return p; };
    float* xbuf   = (float*)alloc((size_t)N * 64 * 4);
    u16*   msg    = (u16*)alloc((size_t)E * 64 * 2);
    u16*   wf2    = (u16*)alloc((size_t)34 * 4 * 512 * 2);
    u16*   ea16   = (u16*)alloc((size_t)E * 16 * 2);
    u16*   w1     = (u16*)alloc(16384 * 2);
    u16*   w2     = (u16*)alloc(12288 * 2);
    u16*   w0     = (u16*)alloc(2048 * 2);
    int*   deg    = (int*)alloc((size_t)N * 4);
    int*   tab    = (int*)alloc((size_t)N * CAP * 4);
    (void)ws_size;

    int nEA = E * 16;
    int nbuild = (E + 255) / 256;
    int ntile  = (N + 63) / 64;

    hipLaunchKernelGGL(k_prep, dim3((nEA + 255) / 256), dim3(256), 0, stream,
                       nn_w, nn_b, root, w_hh, w_ih, lin0_w, ea,
                       wf2, w1, w2, w0, ea16, deg, N, nEA);
    hipLaunchKernelGGL(k_pre2, dim3(nbuild + ntile), dim3(256), 0, stream,
                       ei, deg, tab, x_in, w0, lin0_b, xbuf, N, E);

    for (int it = 0; it < 3; it++) {
        hipLaunchKernelGGL(k_AB, dim3((E + 255) / 256, 2), dim3(256), 0, stream,
                           xbuf, ea16, wf2, ei, msg, E);
        float* hout = (it == 2) ? (float*)d_out : xbuf;
        hipLaunchKernelGGL(k_C, dim3(ntile), dim3(256), 0, stream, xbuf, msg,
                           deg, tab, w1, w2, conv_b, b_hh, b_ih, hout, N);
    }
}

// Round 20
// 180.363 us; speedup vs baseline: 1.5320x; 1.0211x over previous
//
#include <hip/hip_runtime.h>
#include <hip/hip_bf16.h>

typedef unsigned short u16;
typedef __attribute__((ext_vector_type(8))) _Float16 h8v;   // MFMA f16 A/B frag (4 VGPR)
typedef __attribute__((ext_vector_type(4))) float f32x4;    // MFMA C/D frag

#define CAP 32  // max in-degree tracked; E/N=2 (Poisson), P(deg>31) ~ 0

static __device__ __forceinline__ u16 f2h(float f) {
    _Float16 h = (_Float16)f;          // RNE
    u16 r; __builtin_memcpy(&r, &h, 2); return r;
}
static __device__ __forceinline__ float h2f(u16 b) {
    _Float16 h; __builtin_memcpy(&h, &b, 2); return (float)h;
}
static __device__ __forceinline__ float sigm(float x) {
    return 1.f / (1.f + __expf(-x));
}
static __device__ __forceinline__ float tanh_f(float x) {
    return 1.f - 2.f / (__expf(2.f * x) + 1.f);
}

// ---- one-time prep: wf2/w1/w2/w0 pack + deg zero. Grid 272 blocks
// (ea conversion folded into k_AB -> no more E*16-sized grid here).
__global__ __launch_bounds__(256) void k_prep(
        const float* __restrict__ nn_w, const float* __restrict__ nn_b,
        const float* __restrict__ root, const float* __restrict__ w_hh,
        const float* __restrict__ w_ih, const float* __restrict__ lin0_w,
        u16* __restrict__ wf2, u16* __restrict__ w1, u16* __restrict__ w2,
        u16* __restrict__ w0, int* __restrict__ deg, int N) {
    int idx = blockIdx.x * 256 + threadIdx.x;
    // -- wf2: edge-GEMM A-frags. kappa = k*64+i (k-major); kappa>=1024 -> bias (z=x)
    if (idx < 34 * 4 * 512) {
        int j = idx & 7, lane = (idx >> 3) & 63;
        int rest = idx >> 9;
        int ct = rest & 3, kc = rest >> 2;
        int kappa = kc * 32 + ((lane >> 4) * 8) + j;
        int o = ct * 16 + (lane & 15);
        float v;
        if (kappa < 1024) {
            int k = kappa >> 6, i = kappa & 63;
            v = nn_w[(size_t)(i * 64 + o) * 16 + k];
        } else {
            v = nn_b[(size_t)(kappa - 1024) * 64 + o];
        }
        wf2[idx] = f2h(v);
    }
    // -- w1=[root | w_hh^T] (16 ct), w2=w_ih^T (12 ct), w0=lin0_w^T (4 ct)
    if (idx < 16384 + 12288 + 2048) {
        if (idx < 16384) {
            int j = idx & 7, lane = (idx >> 3) & 63;
            int rest = idx >> 9;          // kc*16 + ct
            int ct = rest & 15, kc = rest >> 4;
            int k = kc * 32 + ((lane >> 4) * 8) + j;
            int col = ct * 16 + (lane & 15);
            float v = (col < 64) ? root[(size_t)k * 64 + col]
                                 : w_hh[(size_t)(col - 64) * 64 + k];
            w1[idx] = f2h(v);
        } else if (idx < 16384 + 12288) {
            int i2 = idx - 16384;
            int j = i2 & 7, lane = (i2 >> 3) & 63;
            int rest = i2 >> 9;           // kc*12 + ct
            int ct = rest % 12, kc = rest / 12;
            int k = kc * 32 + ((lane >> 4) * 8) + j;
            int col = ct * 16 + (lane & 15);
            w2[i2] = f2h(w_ih[(size_t)col * 64 + k]);
        } else {
            int i3 = idx - 16384 - 12288;
            int j = i3 & 7, lane = (i3 >> 3) & 63;
            int ct = i3 >> 9;             // 0..3
            int k = ((lane >> 4) * 8) + j;
            int col = ct * 16 + (lane & 15);
            w0[i3] = f2h(lin0_w[(size_t)col * 32 + k]);
        }
    }
    if (idx < N) deg[idx] = 0;
}

// ---- one-time: padded in-edge table build + lin0 in one kernel (R14/R17-proven)
__global__ __launch_bounds__(256) void k_pre2(
        const int* __restrict__ ei, int* __restrict__ deg, int* __restrict__ tab,
        const float* __restrict__ x_in, const u16* __restrict__ w0,
        const float* __restrict__ lin0_b, float* __restrict__ x0,
        int N, int E) {
    int nbuild = (E + 255) / 256;
    int bid = blockIdx.x;
    int t = threadIdx.x;
    if (bid < nbuild) {
        int e = bid * 256 + t;
        if (e < E) {
            int dst = ei[E + e];
            int pos = atomicAdd(&deg[dst], 1);
            if (pos < CAP) tab[(size_t)dst * CAP + pos] = e;
        }
        return;
    }
    // lin0 (MFMA fp16): x0 = relu(x_in[N,32] @ w0 + b). 64 nodes/block.
    int b2 = bid - nbuild;
    int l = t & 63, w = t >> 6, g = l >> 4;
    int n0 = b2 * 64 + w * 16;
    int node = n0 + (l & 15);
    int nc = node < N ? node : N - 1;
    const float* xrow = x_in + (size_t)nc * 32 + g * 8;
    float4 xa = *(const float4*)(xrow);
    float4 xb = *(const float4*)(xrow + 4);
    h8v xh;
    xh[0] = (_Float16)xa.x; xh[1] = (_Float16)xa.y;
    xh[2] = (_Float16)xa.z; xh[3] = (_Float16)xa.w;
    xh[4] = (_Float16)xb.x; xh[5] = (_Float16)xb.y;
    xh[6] = (_Float16)xb.z; xh[7] = (_Float16)xb.w;
    f32x4 acc[4];
    #pragma unroll
    for (int ct = 0; ct < 4; ct++) {
        h8v wh = *(const h8v*)((const _Float16*)w0 + (ct * 64 + l) * 8);
        acc[ct] = __builtin_amdgcn_mfma_f32_16x16x32_f16(wh, xh, (f32x4)(0.f), 0, 0, 0);
    }
    if (node < N) {
        #pragma unroll
        for (int ct = 0; ct < 4; ct++) {
            int c = ct * 16 + g * 4;
            f32x4 bb = *(const f32x4*)(lin0_b + c);
            f32x4 ov;
            #pragma unroll
            for (int r = 0; r < 4; r++) ov[r] = fmaxf(acc[ct][r] + bb[r], 0.f);
            *(f32x4*)(x0 + (size_t)node * 64 + c) = ov;
        }
    }
}

// ---- AB (NNConv message, MFMA fp16, ONCE-staged LDS A-frags) — R15-proven.
// NEW: reads fp32 ea directly (in-register f16 convert) — k_prep no longer
// needs an E*16-sized grid for the ea16 conversion.
__global__ __launch_bounds__(256) void k_AB(
        const float* __restrict__ x, const float* __restrict__ ea,
        const u16* __restrict__ wf2, const int* __restrict__ ei,
        u16* __restrict__ msg, int E) {
    __shared__ __align__(16) u16 Ab[64 * 512];   // 64 KB: kc 0..31, this ct-half
    int t = threadIdx.x, l = t & 63, w = t >> 6, g = l >> 4;
    int ctH = blockIdx.y;             // out-col half: cols ctH*32 .. ctH*32+31
    int eblk = blockIdx.x * 256 + w * 64;

    int eact[4];
    h8v xf0[4], xf1[4], eav[4][2];
    #pragma unroll
    for (int et = 0; et < 4; et++) {
        int e = eblk + et * 16 + (l & 15);
        eact[et] = e;
        int ec = e < E ? e : E - 1;
        int src = ei[ec];
        const float* xr = x + (size_t)src * 64 + g * 8;
        float4 v0 = *(const float4*)(xr);
        float4 v1 = *(const float4*)(xr + 4);
        float4 v2 = *(const float4*)(xr + 32);
        float4 v3 = *(const float4*)(xr + 36);
        h8v a, b;
        a[0] = (_Float16)v0.x; a[1] = (_Float16)v0.y;
        a[2] = (_Float16)v0.z; a[3] = (_Float16)v0.w;
        a[4] = (_Float16)v1.x; a[5] = (_Float16)v1.y;
        a[6] = (_Float16)v1.z; a[7] = (_Float16)v1.w;
        b[0] = (_Float16)v2.x; b[1] = (_Float16)v2.y;
        b[2] = (_Float16)v2.z; b[3] = (_Float16)v2.w;
        b[4] = (_Float16)v3.x; b[5] = (_Float16)v3.y;
        b[6] = (_Float16)v3.z; b[7] = (_Float16)v3.w;
        xf0[et] = a;
        xf1[et] = b;
        const float* ep = ea + (size_t)ec * 16;
        float4 e0 = *(const float4*)(ep);
        float4 e1 = *(const float4*)(ep + 4);
        float4 e2 = *(const float4*)(ep + 8);
        float4 e3 = *(const float4*)(ep + 12);
        h8v ev0, ev1;
        ev0[0] = (_Float16)e0.x; ev0[1] = (_Float16)e0.y;
        ev0[2] = (_Float16)e0.z; ev0[3] = (_Float16)e0.w;
        ev0[4] = (_Float16)e1.x; ev0[5] = (_Float16)e1.y;
        ev0[6] = (_Float16)e1.z; ev0[7] = (_Float16)e1.w;
        ev1[0] = (_Float16)e2.x; ev1[1] = (_Float16)e2.y;
        ev1[2] = (_Float16)e2.z; ev1[3] = (_Float16)e2.w;
        ev1[4] = (_Float16)e3.x; ev1[5] = (_Float16)e3.y;
        ev1[6] = (_Float16)e3.z; ev1[7] = (_Float16)e3.w;
        eav[et][0] = ev0;
        eav[et][1] = ev1;
    }

    const uint4* wf2u = (const uint4*)wf2;
    uint4* Abu = (uint4*)Ab;
    #pragma unroll
    for (int i = 0; i < 16; i++) {
        int j = i * 256 + t;
        int f = j >> 6, win = j & 63;        // f = kc*2+ct (local), win = lane slot
        int gf = (f >> 1) * 4 + ctH * 2 + (f & 1);
        Abu[j] = wf2u[(size_t)gf * 64 + win];
    }
    __syncthreads();   // the ONLY barrier

    f32x4 acc[4][2];
    #pragma unroll
    for (int et = 0; et < 4; et++)
        #pragma unroll
        for (int ct = 0; ct < 2; ct++) acc[et][ct] = (f32x4)(0.f);

    const _Float16* AbH = (const _Float16*)Ab;
    const _Float16* wfh = (const _Float16*)wf2;

    #pragma unroll
    for (int p = 0; p < 8; p++) {
        #pragma unroll
        for (int kcl = 0; kcl < 4; kcl++) {
            int kc = p * 4 + kcl;
            h8v af[2];
            #pragma unroll
            for (int ct = 0; ct < 2; ct++)
                af[ct] = *(const h8v*)(AbH + (size_t)(kc * 2 + ct) * 512 + l * 8);
            const int k = 2 * p + (kcl >> 1);   // compile-time after unroll
            #pragma unroll
            for (int et = 0; et < 4; et++) {
                _Float16 s = eav[et][k >> 3][k & 7];
                h8v es = {s, s, s, s, s, s, s, s};
                h8v zf = es * ((kcl & 1) ? xf1[et] : xf0[et]);
                #pragma unroll
                for (int ct = 0; ct < 2; ct++)
                    acc[et][ct] = __builtin_amdgcn_mfma_f32_16x16x32_f16(af[ct], zf, acc[et][ct], 0, 0, 0);
            }
        }
    }
    // bias block: kc = 32,33 ; z = x fragment; A-frags direct from L2 (hot)
    #pragma unroll
    for (int kcl = 0; kcl < 2; kcl++) {
        int kc = 32 + kcl;
        h8v af[2];
        #pragma unroll
        for (int ct = 0; ct < 2; ct++)
            af[ct] = *(const h8v*)(wfh + (size_t)(kc * 4 + ctH * 2 + ct) * 512 + l * 8);
        #pragma unroll
        for (int et = 0; et < 4; et++) {
            h8v zf = (kcl & 1) ? xf1[et] : xf0[et];
            #pragma unroll
            for (int ct = 0; ct < 2; ct++)
                acc[et][ct] = __builtin_amdgcn_mfma_f32_16x16x32_f16(af[ct], zf, acc[et][ct], 0, 0, 0);
        }
    }

    #pragma unroll
    for (int et = 0; et < 4; et++) {
        int e = eact[et];
        if (e < E) {
            u16* mr = msg + (size_t)e * 64 + g * 4;
            #pragma unroll
            for (int ct = 0; ct < 2; ct++) {
                ushort4 pk;
                pk.x = f2h(acc[et][ct][0]);
                pk.y = f2h(acc[et][ct][1]);
                pk.z = f2h(acc[et][ct][2]);
                pk.w = f2h(acc[et][ct][3]);
                *(ushort4*)(mr + (ctH * 2 + ct) * 16) = pk;
            }
        }
    }
}

// ---- C (fused gather + C1 + C2, MFMA fp16, single barrier) — R17-proven.
__global__ __launch_bounds__(256) void k_C(
        const float* __restrict__ x, const u16* __restrict__ msg,
        const int* __restrict__ deg, const int* __restrict__ tab,
        const u16* __restrict__ w1, const u16* __restrict__ w2,
        const float* __restrict__ conv_b, const float* __restrict__ b_hh,
        const float* __restrict__ b_ih, float* __restrict__ hout, int N) {
    __shared__ float mld[4][16][68];
    int t = threadIdx.x, l = t & 63, w = t >> 6, g = l >> 4;
    int n0 = blockIdx.x * 64 + w * 16;
    int node = n0 + (l & 15);
    int nc = node < N ? node : N - 1;
    const float* xrow = x + (size_t)nc * 64 + g * 8;
    const _Float16* w1h = (const _Float16*)w1;
    const _Float16* w2h = (const _Float16*)w2;

    h8v xh[2];
    #pragma unroll
    for (int kc = 0; kc < 2; kc++) {
        f32x4 a = *(const f32x4*)(xrow + kc * 32);
        f32x4 b = *(const f32x4*)(xrow + kc * 32 + 4);
        #pragma unroll
        for (int j = 0; j < 8; j++) xh[kc][j] = (_Float16)(j < 4 ? a[j] : b[j - 4]);
    }

    // padded-table gather of in-edge messages
    f32x4 avs[4];
    #pragma unroll
    for (int ct = 0; ct < 4; ct++) avs[ct] = (f32x4)(0.f);
    if (node < N) {
        int dg = deg[node];
        dg = dg < CAP ? dg : CAP;
        const int* tr = tab + (size_t)node * CAP;
        for (int j = 0; j < dg; j++) {
            int eid = tr[j];
            const u16* mr = msg + (size_t)eid * 64 + g * 4;
            #pragma unroll
            for (int ct = 0; ct < 4; ct++) {
                ushort4 mv = *(const ushort4*)(mr + ct * 16);
                avs[ct][0] += h2f(mv.x);
                avs[ct][1] += h2f(mv.y);
                avs[ct][2] += h2f(mv.z);
                avs[ct][3] += h2f(mv.w);
            }
        }
    }

    // phase1: A-frags direct from L2 (28 KB shared chip-wide, L2-hot)
    f32x4 acc1[16];
    #pragma unroll
    for (int ct = 0; ct < 16; ct++) acc1[ct] = (f32x4)(0.f);
    #pragma unroll
    for (int kc = 0; kc < 2; kc++) {
        #pragma unroll
        for (int ct = 0; ct < 16; ct++) {
            h8v wh = *(const h8v*)(w1h + (size_t)(kc * 16 + ct) * 512 + l * 8);
            acc1[ct] = __builtin_amdgcn_mfma_f32_16x16x32_f16(wh, xh[kc], acc1[ct], 0, 0, 0);
        }
    }

    // epilogue 1: m -> LDS (16x64 lane transpose); gh = acc1[4..15]+b_hh
    #pragma unroll
    for (int ct = 0; ct < 4; ct++) {
        int c = ct * 16 + g * 4;
        f32x4 cb = *(const f32x4*)(conv_b + c);
        f32x4 mv;
        #pragma unroll
        for (int r = 0; r < 4; r++) mv[r] = fmaxf(acc1[ct][r] + avs[ct][r] + cb[r], 0.f);
        *(f32x4*)(&mld[w][l & 15][c]) = mv;
    }
    #pragma unroll
    for (int ct = 4; ct < 16; ct++) {
        int c = (ct - 4) * 16 + g * 4;
        f32x4 bh = *(const f32x4*)(b_hh + c);
        #pragma unroll
        for (int r = 0; r < 4; r++) acc1[ct][r] += bh[r];
    }
    __syncthreads();   // fence for the cross-lane LDS transpose (R9 lesson)

    h8v mh[2];
    #pragma unroll
    for (int kc = 0; kc < 2; kc++) {
        const float* mr = &mld[w][l & 15][kc * 32 + g * 8];
        f32x4 a = *(const f32x4*)(mr);
        f32x4 b = *(const f32x4*)(mr + 4);
        #pragma unroll
        for (int j = 0; j < 8; j++) mh[kc][j] = (_Float16)(j < 4 ? a[j] : b[j - 4]);
    }

    // phase2
    f32x4 acc2[12];
    #pragma unroll
    for (int ct = 0; ct < 12; ct++) acc2[ct] = (f32x4)(0.f);
    #pragma unroll
    for (int kc = 0; kc < 2; kc++) {
        #pragma unroll
        for (int ct = 0; ct < 12; ct++) {
            h8v wh = *(const h8v*)(w2h + (size_t)(kc * 12 + ct) * 512 + l * 8);
            acc2[ct] = __builtin_amdgcn_mfma_f32_16x16x32_f16(wh, mh[kc], acc2[ct], 0, 0, 0);
        }
    }

    // epilogue 2: gates (all lane-local)
    #pragma unroll
    for (int q = 0; q < 4; q++) {
        int c = q * 16 + g * 4;
        f32x4 bir = *(const f32x4*)(b_ih + c);
        f32x4 biz = *(const f32x4*)(b_ih + 64 + c);
        f32x4 bin = *(const f32x4*)(b_ih + 128 + c);
        f32x4 hv = (f32x4)(0.f);
        if (node < N) hv = *(const f32x4*)(x + (size_t)node * 64 + c);
        f32x4 outv;
        #pragma unroll
        for (int r = 0; r < 4; r++) {
            float rr = sigm(acc2[q][r] + bir[r] + acc1[4 + q][r]);
            float zz = sigm(acc2[4 + q][r] + biz[r] + acc1[8 + q][r]);
            float nt = tanh_f(acc2[8 + q][r] + bin[r] + rr * acc1[12 + q][r]);
            outv[r] = (1.f - zz) * nt + zz * hv[r];
        }
        if (node < N) *(f32x4*)(hout + (size_t)node * 64 + c) = outv;
    }
}

extern "C" void kernel_launch(void* const* d_in, const int* in_sizes, int n_in,
                              void* d_out, int out_size, void* d_ws, size_t ws_size,
                              hipStream_t stream) {
    const float* x_in   = (const float*)d_in[0];
    const int*   ei     = (const int*)d_in[1];
    const float* ea     = (const float*)d_in[2];
    const float* lin0_w = (const float*)d_in[3];
    const float* lin0_b = (const float*)d_in[4];
    const float* nn_w   = (const float*)d_in[5];
    const float* nn_b   = (const float*)d_in[6];
    const float* root   = (const float*)d_in[7];
    const float* conv_b = (const float*)d_in[8];
    const float* w_ih   = (const float*)d_in[9];
    const float* w_hh   = (const float*)d_in[10];
    const float* b_ih   = (const float*)d_in[11];
    const float* b_hh   = (const float*)d_in[12];

    int N = in_sizes[0] / 32;
    int E = in_sizes[1] / 2;

    char* ws = (char*)d_ws;
    size_t off = 0;
    auto alloc = [&](size_t bytes) { char* p = ws + off; off += (bytes + 255) & ~(size_t)255; return p; };
    float* xbuf   = (float*)alloc((size_t)N * 64 * 4);
    u16*   msg    = (u16*)alloc((size_t)E * 64 * 2);
    u16*   wf2    = (u16*)alloc((size_t)34 * 4 * 512 * 2);
    u16*   w1     = (u16*)alloc(16384 * 2);
    u16*   w2     = (u16*)alloc(12288 * 2);
    u16*   w0     = (u16*)alloc(2048 * 2);
    int*   deg    = (int*)alloc((size_t)N * 4);
    int*   tab    = (int*)alloc((size_t)N * CAP * 4);
    (void)ws_size;

    int nprep = 34 * 4 * 512;                  // largest prep job (69632)
    int nbuild = (E + 255) / 256;
    int ntile  = (N + 63) / 64;

    hipLaunchKernelGGL(k_prep, dim3((nprep + 255) / 256), dim3(256), 0, stream,
                       nn_w, nn_b, root, w_hh, w_ih, lin0_w,
                       wf2, w1, w2, w0, deg, N);
    hipLaunchKernelGGL(k_pre2, dim3(nbuild + ntile), dim3(256), 0, stream,
                       ei, deg, tab, x_in, w0, lin0_b, xbuf, N, E);

    for (int it = 0; it < 3; it++) {
        hipLaunchKernelGGL(k_AB, dim3((E + 255) / 256, 2), dim3(256), 0, stream,
                           xbuf, ea, wf2, ei, msg, E);
        float* hout = (it == 2) ? (float*)d_out : xbuf;
        hipLaunchKernelGGL(k_C, dim3(ntile), dim3(256), 0, stream, xbuf, msg,
                           deg, tab, w1, w2, conv_b, b_hh, b_ih, hout, N);
    }
}

// Round 21
// 173.630 us; speedup vs baseline: 1.5914x; 1.0388x over previous
//
#include <hip/hip_runtime.h>
#include <hip/hip_bf16.h>

typedef unsigned short u16;
typedef __attribute__((ext_vector_type(8))) _Float16 h8v;   // MFMA f16 A/B frag (4 VGPR)
typedef __attribute__((ext_vector_type(4))) float f32x4;    // MFMA C/D frag

#define CAP 32  // max in-degree tracked; E/N=2 (Poisson), P(deg>31) ~ 0

static __device__ __forceinline__ u16 f2h(float f) {
    _Float16 h = (_Float16)f;          // RNE
    u16 r; __builtin_memcpy(&r, &h, 2); return r;
}
static __device__ __forceinline__ float h2f(u16 b) {
    _Float16 h; __builtin_memcpy(&h, &b, 2); return (float)h;
}
static __device__ __forceinline__ float sigm(float x) {
    return 1.f / (1.f + __expf(-x));
}
static __device__ __forceinline__ float tanh_f(float x) {
    return 1.f - 2.f / (__expf(2.f * x) + 1.f);
}

// ---- one-time merged prep: wf2 pack, w1/w2/w0 pack, ea->fp16, deg zero.
__global__ __launch_bounds__(256) void k_prep(
        const float* __restrict__ nn_w, const float* __restrict__ nn_b,
        const float* __restrict__ root, const float* __restrict__ w_hh,
        const float* __restrict__ w_ih, const float* __restrict__ lin0_w,
        const float* __restrict__ ea,
        u16* __restrict__ wf2, u16* __restrict__ w1, u16* __restrict__ w2,
        u16* __restrict__ w0, u16* __restrict__ ea16, int* __restrict__ deg,
        int N, int nEA) {
    int idx = blockIdx.x * 256 + threadIdx.x;
    // -- wf2: edge-GEMM A-frags. kappa = k*64+i (k-major); kappa>=1024 -> bias (z=x)
    if (idx < 34 * 4 * 512) {
        int j = idx & 7, lane = (idx >> 3) & 63;
        int rest = idx >> 9;
        int ct = rest & 3, kc = rest >> 2;
        int kappa = kc * 32 + ((lane >> 4) * 8) + j;
        int o = ct * 16 + (lane & 15);
        float v;
        if (kappa < 1024) {
            int k = kappa >> 6, i = kappa & 63;
            v = nn_w[(size_t)(i * 64 + o) * 16 + k];
        } else {
            v = nn_b[(size_t)(kappa - 1024) * 64 + o];
        }
        wf2[idx] = f2h(v);
    }
    // -- w1=[root | w_hh^T] (16 ct), w2=w_ih^T (12 ct), w0=lin0_w^T (4 ct)
    if (idx < 16384 + 12288 + 2048) {
        if (idx < 16384) {
            int j = idx & 7, lane = (idx >> 3) & 63;
            int rest = idx >> 9;          // kc*16 + ct
            int ct = rest & 15, kc = rest >> 4;
            int k = kc * 32 + ((lane >> 4) * 8) + j;
            int col = ct * 16 + (lane & 15);
            float v = (col < 64) ? root[(size_t)k * 64 + col]
                                 : w_hh[(size_t)(col - 64) * 64 + k];
            w1[idx] = f2h(v);
        } else if (idx < 16384 + 12288) {
            int i2 = idx - 16384;
            int j = i2 & 7, lane = (i2 >> 3) & 63;
            int rest = i2 >> 9;           // kc*12 + ct
            int ct = rest % 12, kc = rest / 12;
            int k = kc * 32 + ((lane >> 4) * 8) + j;
            int col = ct * 16 + (lane & 15);
            w2[i2] = f2h(w_ih[(size_t)col * 64 + k]);
        } else {
            int i3 = idx - 16384 - 12288;
            int j = i3 & 7, lane = (i3 >> 3) & 63;
            int ct = i3 >> 9;             // 0..3
            int k = ((lane >> 4) * 8) + j;
            int col = ct * 16 + (lane & 15);
            w0[i3] = f2h(lin0_w[(size_t)col * 32 + k]);
        }
    }
    if (idx < N) deg[idx] = 0;
    if (idx < nEA) ea16[idx] = f2h(ea[idx]);
}

// ---- one-time: padded in-edge table build + lin0 in one kernel (R14/R17-proven)
__global__ __launch_bounds__(256) void k_pre2(
        const int* __restrict__ ei, int* __restrict__ deg, int* __restrict__ tab,
        const float* __restrict__ x_in, const u16* __restrict__ w0,
        const float* __restrict__ lin0_b, float* __restrict__ x0,
        int N, int E) {
    int nbuild = (E + 255) / 256;
    int bid = blockIdx.x;
    int t = threadIdx.x;
    if (bid < nbuild) {
        int e = bid * 256 + t;
        if (e < E) {
            int dst = ei[E + e];
            int pos = atomicAdd(&deg[dst], 1);
            if (pos < CAP) tab[(size_t)dst * CAP + pos] = e;
        }
        return;
    }
    // lin0 (MFMA fp16): x0 = relu(x_in[N,32] @ w0 + b). 64 nodes/block.
    int b2 = bid - nbuild;
    int l = t & 63, w = t >> 6, g = l >> 4;
    int n0 = b2 * 64 + w * 16;
    int node = n0 + (l & 15);
    int nc = node < N ? node : N - 1;
    const float* xrow = x_in + (size_t)nc * 32 + g * 8;
    float4 xa = *(const float4*)(xrow);
    float4 xb = *(const float4*)(xrow + 4);
    h8v xh;
    xh[0] = (_Float16)xa.x; xh[1] = (_Float16)xa.y;
    xh[2] = (_Float16)xa.z; xh[3] = (_Float16)xa.w;
    xh[4] = (_Float16)xb.x; xh[5] = (_Float16)xb.y;
    xh[6] = (_Float16)xb.z; xh[7] = (_Float16)xb.w;
    f32x4 acc[4];
    #pragma unroll
    for (int ct = 0; ct < 4; ct++) {
        h8v wh = *(const h8v*)((const _Float16*)w0 + (ct * 64 + l) * 8);
        acc[ct] = __builtin_amdgcn_mfma_f32_16x16x32_f16(wh, xh, (f32x4)(0.f), 0, 0, 0);
    }
    if (node < N) {
        #pragma unroll
        for (int ct = 0; ct < 4; ct++) {
            int c = ct * 16 + g * 4;
            f32x4 bb = *(const f32x4*)(lin0_b + c);
            f32x4 ov;
            #pragma unroll
            for (int r = 0; r < 4; r++) ov[r] = fmaxf(acc[ct][r] + bb[r], 0.f);
            *(f32x4*)(x0 + (size_t)node * 64 + c) = ov;
        }
    }
}

// ---- AB (NNConv message, MFMA fp16, ONCE-staged LDS A-frags) — R15-proven.
__global__ __launch_bounds__(256) void k_AB(
        const float* __restrict__ x, const u16* __restrict__ ea16,
        const u16* __restrict__ wf2, const int* __restrict__ ei,
        u16* __restrict__ msg, int E) {
    __shared__ __align__(16) u16 Ab[64 * 512];   // 64 KB: kc 0..31, this ct-half
    int t = threadIdx.x, l = t & 63, w = t >> 6, g = l >> 4;
    int ctH = blockIdx.y;             // out-col half: cols ctH*32 .. ctH*32+31
    int eblk = blockIdx.x * 256 + w * 64;

    int eact[4];
    h8v xf0[4], xf1[4], eav[4][2];
    #pragma unroll
    for (int et = 0; et < 4; et++) {
        int e = eblk + et * 16 + (l & 15);
        eact[et] = e;
        int ec = e < E ? e : E - 1;
        int src = ei[ec];
        const float* xr = x + (size_t)src * 64 + g * 8;
        float4 v0 = *(const float4*)(xr);
        float4 v1 = *(const float4*)(xr + 4);
        float4 v2 = *(const float4*)(xr + 32);
        float4 v3 = *(const float4*)(xr + 36);
        h8v a, b;
        a[0] = (_Float16)v0.x; a[1] = (_Float16)v0.y;
        a[2] = (_Float16)v0.z; a[3] = (_Float16)v0.w;
        a[4] = (_Float16)v1.x; a[5] = (_Float16)v1.y;
        a[6] = (_Float16)v1.z; a[7] = (_Float16)v1.w;
        b[0] = (_Float16)v2.x; b[1] = (_Float16)v2.y;
        b[2] = (_Float16)v2.z; b[3] = (_Float16)v2.w;
        b[4] = (_Float16)v3.x; b[5] = (_Float16)v3.y;
        b[6] = (_Float16)v3.z; b[7] = (_Float16)v3.w;
        xf0[et] = a;
        xf1[et] = b;
        const _Float16* ep = (const _Float16*)ea16 + (size_t)ec * 16;
        eav[et][0] = *(const h8v*)(ep);
        eav[et][1] = *(const h8v*)(ep + 8);
    }

    const uint4* wf2u = (const uint4*)wf2;
    uint4* Abu = (uint4*)Ab;
    #pragma unroll
    for (int i = 0; i < 16; i++) {
        int j = i * 256 + t;
        int f = j >> 6, win = j & 63;        // f = kc*2+ct (local), win = lane slot
        int gf = (f >> 1) * 4 + ctH * 2 + (f & 1);
        Abu[j] = wf2u[(size_t)gf * 64 + win];
    }
    __syncthreads();   // the ONLY barrier

    f32x4 acc[4][2];
    #pragma unroll
    for (int et = 0; et < 4; et++)
        #pragma unroll
        for (int ct = 0; ct < 2; ct++) acc[et][ct] = (f32x4)(0.f);

    const _Float16* AbH = (const _Float16*)Ab;
    const _Float16* wfh = (const _Float16*)wf2;

    #pragma unroll
    for (int p = 0; p < 8; p++) {
        #pragma unroll
        for (int kcl = 0; kcl < 4; kcl++) {
            int kc = p * 4 + kcl;
            h8v af[2];
            #pragma unroll
            for (int ct = 0; ct < 2; ct++)
                af[ct] = *(const h8v*)(AbH + (size_t)(kc * 2 + ct) * 512 + l * 8);
            const int k = 2 * p + (kcl >> 1);   // compile-time after unroll
            #pragma unroll
            for (int et = 0; et < 4; et++) {
                _Float16 s = eav[et][k >> 3][k & 7];
                h8v es = {s, s, s, s, s, s, s, s};
                h8v zf = es * ((kcl & 1) ? xf1[et] : xf0[et]);
                #pragma unroll
                for (int ct = 0; ct < 2; ct++)
                    acc[et][ct] = __builtin_amdgcn_mfma_f32_16x16x32_f16(af[ct], zf, acc[et][ct], 0, 0, 0);
            }
        }
    }
    // bias block: kc = 32,33 ; z = x fragment; A-frags direct from L2 (hot)
    #pragma unroll
    for (int kcl = 0; kcl < 2; kcl++) {
        int kc = 32 + kcl;
        h8v af[2];
        #pragma unroll
        for (int ct = 0; ct < 2; ct++)
            af[ct] = *(const h8v*)(wfh + (size_t)(kc * 4 + ctH * 2 + ct) * 512 + l * 8);
        #pragma unroll
        for (int et = 0; et < 4; et++) {
            h8v zf = (kcl & 1) ? xf1[et] : xf0[et];
            #pragma unroll
            for (int ct = 0; ct < 2; ct++)
                acc[et][ct] = __builtin_amdgcn_mfma_f32_16x16x32_f16(af[ct], zf, acc[et][ct], 0, 0, 0);
        }
    }

    #pragma unroll
    for (int et = 0; et < 4; et++) {
        int e = eact[et];
        if (e < E) {
            u16* mr = msg + (size_t)e * 64 + g * 4;
            #pragma unroll
            for (int ct = 0; ct < 2; ct++) {
                ushort4 pk;
                pk.x = f2h(acc[et][ct][0]);
                pk.y = f2h(acc[et][ct][1]);
                pk.z = f2h(acc[et][ct][2]);
                pk.w = f2h(acc[et][ct][3]);
                *(ushort4*)(mr + (ctH * 2 + ct) * 16) = pk;
            }
        }
    }
}

// ---- C (fused gather + C1 + C2, MFMA fp16, single barrier) — R17-proven.
__global__ __launch_bounds__(256) void k_C(
        const float* __restrict__ x, const u16* __restrict__ msg,
        const int* __restrict__ deg, const int* __restrict__ tab,
        const u16* __restrict__ w1, const u16* __restrict__ w2,
        const float* __restrict__ conv_b, const float* __restrict__ b_hh,
        const float* __restrict__ b_ih, float* __restrict__ hout, int N) {
    __shared__ float mld[4][16][68];
    int t = threadIdx.x, l = t & 63, w = t >> 6, g = l >> 4;
    int n0 = blockIdx.x * 64 + w * 16;
    int node = n0 + (l & 15);
    int nc = node < N ? node : N - 1;
    const float* xrow = x + (size_t)nc * 64 + g * 8;
    const _Float16* w1h = (const _Float16*)w1;
    const _Float16* w2h = (const _Float16*)w2;

    h8v xh[2];
    #pragma unroll
    for (int kc = 0; kc < 2; kc++) {
        f32x4 a = *(const f32x4*)(xrow + kc * 32);
        f32x4 b = *(const f32x4*)(xrow + kc * 32 + 4);
        #pragma unroll
        for (int j = 0; j < 8; j++) xh[kc][j] = (_Float16)(j < 4 ? a[j] : b[j - 4]);
    }

    // padded-table gather of in-edge messages
    f32x4 avs[4];
    #pragma unroll
    for (int ct = 0; ct < 4; ct++) avs[ct] = (f32x4)(0.f);
    if (node < N) {
        int dg = deg[node];
        dg = dg < CAP ? dg : CAP;
        const int* tr = tab + (size_t)node * CAP;
        for (int j = 0; j < dg; j++) {
            int eid = tr[j];
            const u16* mr = msg + (size_t)eid * 64 + g * 4;
            #pragma unroll
            for (int ct = 0; ct < 4; ct++) {
                ushort4 mv = *(const ushort4*)(mr + ct * 16);
                avs[ct][0] += h2f(mv.x);
                avs[ct][1] += h2f(mv.y);
                avs[ct][2] += h2f(mv.z);
                avs[ct][3] += h2f(mv.w);
            }
        }
    }

    // phase1: A-frags direct from L2 (28 KB shared chip-wide, L2-hot)
    f32x4 acc1[16];
    #pragma unroll
    for (int ct = 0; ct < 16; ct++) acc1[ct] = (f32x4)(0.f);
    #pragma unroll
    for (int kc = 0; kc < 2; kc++) {
        #pragma unroll
        for (int ct = 0; ct < 16; ct++) {
            h8v wh = *(const h8v*)(w1h + (size_t)(kc * 16 + ct) * 512 + l * 8);
            acc1[ct] = __builtin_amdgcn_mfma_f32_16x16x32_f16(wh, xh[kc], acc1[ct], 0, 0, 0);
        }
    }

    // epilogue 1: m -> LDS (16x64 lane transpose); gh = acc1[4..15]+b_hh
    #pragma unroll
    for (int ct = 0; ct < 4; ct++) {
        int c = ct * 16 + g * 4;
        f32x4 cb = *(const f32x4*)(conv_b + c);
        f32x4 mv;
        #pragma unroll
        for (int r = 0; r < 4; r++) mv[r] = fmaxf(acc1[ct][r] + avs[ct][r] + cb[r], 0.f);
        *(f32x4*)(&mld[w][l & 15][c]) = mv;
    }
    #pragma unroll
    for (int ct = 4; ct < 16; ct++) {
        int c = (ct - 4) * 16 + g * 4;
        f32x4 bh = *(const f32x4*)(b_hh + c);
        #pragma unroll
        for (int r = 0; r < 4; r++) acc1[ct][r] += bh[r];
    }
    __syncthreads();   // fence for the cross-lane LDS transpose (R9 lesson)

    h8v mh[2];
    #pragma unroll
    for (int kc = 0; kc < 2; kc++) {
        const float* mr = &mld[w][l & 15][kc * 32 + g * 8];
        f32x4 a = *(const f32x4*)(mr);
        f32x4 b = *(const f32x4*)(mr + 4);
        #pragma unroll
        for (int j = 0; j < 8; j++) mh[kc][j] = (_Float16)(j < 4 ? a[j] : b[j - 4]);
    }

    // phase2
    f32x4 acc2[12];
    #pragma unroll
    for (int ct = 0; ct < 12; ct++) acc2[ct] = (f32x4)(0.f);
    #pragma unroll
    for (int kc = 0; kc < 2; kc++) {
        #pragma unroll
        for (int ct = 0; ct < 12; ct++) {
            h8v wh = *(const h8v*)(w2h + (size_t)(kc * 12 + ct) * 512 + l * 8);
            acc2[ct] = __builtin_amdgcn_mfma_f32_16x16x32_f16(wh, mh[kc], acc2[ct], 0, 0, 0);
        }
    }

    // epilogue 2: gates (all lane-local)
    #pragma unroll
    for (int q = 0; q < 4; q++) {
        int c = q * 16 + g * 4;
        f32x4 bir = *(const f32x4*)(b_ih + c);
        f32x4 biz = *(const f32x4*)(b_ih + 64 + c);
        f32x4 bin = *(const f32x4*)(b_ih + 128 + c);
        f32x4 hv = (f32x4)(0.f);
        if (node < N) hv = *(const f32x4*)(x + (size_t)node * 64 + c);
        f32x4 outv;
        #pragma unroll
        for (int r = 0; r < 4; r++) {
            float rr = sigm(acc2[q][r] + bir[r] + acc1[4 + q][r]);
            float zz = sigm(acc2[4 + q][r] + biz[r] + acc1[8 + q][r]);
            float nt = tanh_f(acc2[8 + q][r] + bin[r] + rr * acc1[12 + q][r]);
            outv[r] = (1.f - zz) * nt + zz * hv[r];
        }
        if (node < N) *(f32x4*)(hout + (size_t)node * 64 + c) = outv;
    }
}

extern "C" void kernel_launch(void* const* d_in, const int* in_sizes, int n_in,
                              void* d_out, int out_size, void* d_ws, size_t ws_size,
                              hipStream_t stream) {
    const float* x_in   = (const float*)d_in[0];
    const int*   ei     = (const int*)d_in[1];
    const float* ea     = (const float*)d_in[2];
    const float* lin0_w = (const float*)d_in[3];
    const float* lin0_b = (const float*)d_in[4];
    const float* nn_w   = (const float*)d_in[5];
    const float* nn_b   = (const float*)d_in[6];
    const float* root   = (const float*)d_in[7];
    const float* conv_b = (const float*)d_in[8];
    const float* w_ih   = (const float*)d_in[9];
    const float* w_hh   = (const float*)d_in[10];
    const float* b_ih   = (const float*)d_in[11];
    const float* b_hh   = (const float*)d_in[12];

    int N = in_sizes[0] / 32;
    int E = in_sizes[1] / 2;

    char* ws = (char*)d_ws;
    size_t off = 0;
    auto alloc = [&](size_t bytes) { char* p = ws + off; off += (bytes + 255) & ~(size_t)255; return p; };
    float* xbuf   = (float*)alloc((size_t)N * 64 * 4);
    u16*   msg    = (u16*)alloc((size_t)E * 64 * 2);
    u16*   wf2    = (u16*)alloc((size_t)34 * 4 * 512 * 2);
    u16*   ea16   = (u16*)alloc((size_t)E * 16 * 2);
    u16*   w1     = (u16*)alloc(16384 * 2);
    u16*   w2     = (u16*)alloc(12288 * 2);
    u16*   w0     = (u16*)alloc(2048 * 2);
    int*   deg    = (int*)alloc((size_t)N * 4);
    int*   tab    = (int*)alloc((size_t)N * CAP * 4);
    (void)ws_size;

    int nEA = E * 16;
    int nbuild = (E + 255) / 256;
    int ntile  = (N + 63) / 64;

    hipLaunchKernelGGL(k_prep, dim3((nEA + 255) / 256), dim3(256), 0, stream,
                       nn_w, nn_b, root, w_hh, w_ih, lin0_w, ea,
                       wf2, w1, w2, w0, ea16, deg, N, nEA);
    hipLaunchKernelGGL(k_pre2, dim3(nbuild + ntile), dim3(256), 0, stream,
                       ei, deg, tab, x_in, w0, lin0_b, xbuf, N, E);

    for (int it = 0; it < 3; it++) {
        hipLaunchKernelGGL(k_AB, dim3((E + 255) / 256, 2), dim3(256), 0, stream,
                           xbuf, ea16, wf2, ei, msg, E);
        float* hout = (it == 2) ? (float*)d_out : xbuf;
        hipLaunchKernelGGL(k_C, dim3(ntile), dim3(256), 0, stream, xbuf, msg,
                           deg, tab, w1, w2, conv_b, b_hh, b_ih, hout, N);
    }
}

// Round 22
// 169.346 us; speedup vs baseline: 1.6317x; 1.0253x over previous
//
#include <hip/hip_runtime.h>
#include <hip/hip_bf16.h>

typedef unsigned short u16;
typedef __attribute__((ext_vector_type(8))) _Float16 h8v;   // MFMA f16 A/B frag (4 VGPR)
typedef __attribute__((ext_vector_type(4))) float f32x4;    // MFMA C/D frag

#define CAP 32  // max in-degree tracked; E/N=2 (Poisson), P(deg>31) ~ 0

static __device__ __forceinline__ u16 f2h(float f) {
    _Float16 h = (_Float16)f;          // RNE
    u16 r; __builtin_memcpy(&r, &h, 2); return r;
}
static __device__ __forceinline__ float h2f(u16 b) {
    _Float16 h; __builtin_memcpy(&h, &b, 2); return (float)h;
}
static __device__ __forceinline__ float sigm(float x) {
    return 1.f / (1.f + __expf(-x));
}
static __device__ __forceinline__ float tanh_f(float x) {
    return 1.f - 2.f / (__expf(2.f * x) + 1.f);
}

// ---- one-time merged prep: wf2 pack, w1/w2/w0 pack, ea->fp16, deg zero.
__global__ __launch_bounds__(256) void k_prep(
        const float* __restrict__ nn_w, const float* __restrict__ nn_b,
        const float* __restrict__ root, const float* __restrict__ w_hh,
        const float* __restrict__ w_ih, const float* __restrict__ lin0_w,
        const float* __restrict__ ea,
        u16* __restrict__ wf2, u16* __restrict__ w1, u16* __restrict__ w2,
        u16* __restrict__ w0, u16* __restrict__ ea16, int* __restrict__ deg,
        int N, int nEA) {
    int idx = blockIdx.x * 256 + threadIdx.x;
    // -- wf2: edge-GEMM A-frags. kappa = k*64+i (k-major); kappa>=1024 -> bias (z=x)
    if (idx < 34 * 4 * 512) {
        int j = idx & 7, lane = (idx >> 3) & 63;
        int rest = idx >> 9;
        int ct = rest & 3, kc = rest >> 2;
        int kappa = kc * 32 + ((lane >> 4) * 8) + j;
        int o = ct * 16 + (lane & 15);
        float v;
        if (kappa < 1024) {
            int k = kappa >> 6, i = kappa & 63;
            v = nn_w[(size_t)(i * 64 + o) * 16 + k];
        } else {
            v = nn_b[(size_t)(kappa - 1024) * 64 + o];
        }
        wf2[idx] = f2h(v);
    }
    // -- w1=[root | w_hh^T] (16 ct), w2=w_ih^T (12 ct), w0=lin0_w^T (4 ct)
    if (idx < 16384 + 12288 + 2048) {
        if (idx < 16384) {
            int j = idx & 7, lane = (idx >> 3) & 63;
            int rest = idx >> 9;          // kc*16 + ct
            int ct = rest & 15, kc = rest >> 4;
            int k = kc * 32 + ((lane >> 4) * 8) + j;
            int col = ct * 16 + (lane & 15);
            float v = (col < 64) ? root[(size_t)k * 64 + col]
                                 : w_hh[(size_t)(col - 64) * 64 + k];
            w1[idx] = f2h(v);
        } else if (idx < 16384 + 12288) {
            int i2 = idx - 16384;
            int j = i2 & 7, lane = (i2 >> 3) & 63;
            int rest = i2 >> 9;           // kc*12 + ct
            int ct = rest % 12, kc = rest / 12;
            int k = kc * 32 + ((lane >> 4) * 8) + j;
            int col = ct * 16 + (lane & 15);
            w2[i2] = f2h(w_ih[(size_t)col * 64 + k]);
        } else {
            int i3 = idx - 16384 - 12288;
            int j = i3 & 7, lane = (i3 >> 3) & 63;
            int ct = i3 >> 9;             // 0..3
            int k = ((lane >> 4) * 8) + j;
            int col = ct * 16 + (lane & 15);
            w0[i3] = f2h(lin0_w[(size_t)col * 32 + k]);
        }
    }
    if (idx < N) deg[idx] = 0;
    if (idx < nEA) ea16[idx] = f2h(ea[idx]);
}

// ---- one-time: padded in-edge table build + lin0 in one kernel (R14/R17-proven)
__global__ __launch_bounds__(256) void k_pre2(
        const int* __restrict__ ei, int* __restrict__ deg, int* __restrict__ tab,
        const float* __restrict__ x_in, const u16* __restrict__ w0,
        const float* __restrict__ lin0_b, float* __restrict__ x0,
        int N, int E) {
    int nbuild = (E + 255) / 256;
    int bid = blockIdx.x;
    int t = threadIdx.x;
    if (bid < nbuild) {
        int e = bid * 256 + t;
        if (e < E) {
            int dst = ei[E + e];
            int pos = atomicAdd(&deg[dst], 1);
            if (pos < CAP) tab[(size_t)dst * CAP + pos] = e;
        }
        return;
    }
    // lin0 (MFMA fp16): x0 = relu(x_in[N,32] @ w0 + b). 64 nodes/block.
    int b2 = bid - nbuild;
    int l = t & 63, w = t >> 6, g = l >> 4;
    int n0 = b2 * 64 + w * 16;
    int node = n0 + (l & 15);
    int nc = node < N ? node : N - 1;
    const float* xrow = x_in + (size_t)nc * 32 + g * 8;
    float4 xa = *(const float4*)(xrow);
    float4 xb = *(const float4*)(xrow + 4);
    h8v xh;
    xh[0] = (_Float16)xa.x; xh[1] = (_Float16)xa.y;
    xh[2] = (_Float16)xa.z; xh[3] = (_Float16)xa.w;
    xh[4] = (_Float16)xb.x; xh[5] = (_Float16)xb.y;
    xh[6] = (_Float16)xb.z; xh[7] = (_Float16)xb.w;
    f32x4 acc[4];
    #pragma unroll
    for (int ct = 0; ct < 4; ct++) {
        h8v wh = *(const h8v*)((const _Float16*)w0 + (ct * 64 + l) * 8);
        acc[ct] = __builtin_amdgcn_mfma_f32_16x16x32_f16(wh, xh, (f32x4)(0.f), 0, 0, 0);
    }
    if (node < N) {
        #pragma unroll
        for (int ct = 0; ct < 4; ct++) {
            int c = ct * 16 + g * 4;
            f32x4 bb = *(const f32x4*)(lin0_b + c);
            f32x4 ov;
            #pragma unroll
            for (int r = 0; r < 4; r++) ov[r] = fmaxf(acc[ct][r] + bb[r], 0.f);
            *(f32x4*)(x0 + (size_t)node * 64 + c) = ov;
        }
    }
}

// ---- AB (NNConv message, MFMA fp16, ONCE-staged LDS A-frags) — R15-proven.
__global__ __launch_bounds__(256) void k_AB(
        const float* __restrict__ x, const u16* __restrict__ ea16,
        const u16* __restrict__ wf2, const int* __restrict__ ei,
        u16* __restrict__ msg, int E) {
    __shared__ __align__(16) u16 Ab[64 * 512];   // 64 KB: kc 0..31, this ct-half
    int t = threadIdx.x, l = t & 63, w = t >> 6, g = l >> 4;
    int ctH = blockIdx.y;             // out-col half: cols ctH*32 .. ctH*32+31
    int eblk = blockIdx.x * 256 + w * 64;

    int eact[4];
    h8v xf0[4], xf1[4], eav[4][2];
    #pragma unroll
    for (int et = 0; et < 4; et++) {
        int e = eblk + et * 16 + (l & 15);
        eact[et] = e;
        int ec = e < E ? e : E - 1;
        int src = ei[ec];
        const float* xr = x + (size_t)src * 64 + g * 8;
        float4 v0 = *(const float4*)(xr);
        float4 v1 = *(const float4*)(xr + 4);
        float4 v2 = *(const float4*)(xr + 32);
        float4 v3 = *(const float4*)(xr + 36);
        h8v a, b;
        a[0] = (_Float16)v0.x; a[1] = (_Float16)v0.y;
        a[2] = (_Float16)v0.z; a[3] = (_Float16)v0.w;
        a[4] = (_Float16)v1.x; a[5] = (_Float16)v1.y;
        a[6] = (_Float16)v1.z; a[7] = (_Float16)v1.w;
        b[0] = (_Float16)v2.x; b[1] = (_Float16)v2.y;
        b[2] = (_Float16)v2.z; b[3] = (_Float16)v2.w;
        b[4] = (_Float16)v3.x; b[5] = (_Float16)v3.y;
        b[6] = (_Float16)v3.z; b[7] = (_Float16)v3.w;
        xf0[et] = a;
        xf1[et] = b;
        const _Float16* ep = (const _Float16*)ea16 + (size_t)ec * 16;
        eav[et][0] = *(const h8v*)(ep);
        eav[et][1] = *(const h8v*)(ep + 8);
    }

    const uint4* wf2u = (const uint4*)wf2;
    uint4* Abu = (uint4*)Ab;
    #pragma unroll
    for (int i = 0; i < 16; i++) {
        int j = i * 256 + t;
        int f = j >> 6, win = j & 63;        // f = kc*2+ct (local), win = lane slot
        int gf = (f >> 1) * 4 + ctH * 2 + (f & 1);
        Abu[j] = wf2u[(size_t)gf * 64 + win];
    }
    __syncthreads();   // the ONLY barrier

    f32x4 acc[4][2];
    #pragma unroll
    for (int et = 0; et < 4; et++)
        #pragma unroll
        for (int ct = 0; ct < 2; ct++) acc[et][ct] = (f32x4)(0.f);

    const _Float16* AbH = (const _Float16*)Ab;
    const _Float16* wfh = (const _Float16*)wf2;

    #pragma unroll
    for (int p = 0; p < 8; p++) {
        #pragma unroll
        for (int kcl = 0; kcl < 4; kcl++) {
            int kc = p * 4 + kcl;
            h8v af[2];
            #pragma unroll
            for (int ct = 0; ct < 2; ct++)
                af[ct] = *(const h8v*)(AbH + (size_t)(kc * 2 + ct) * 512 + l * 8);
            const int k = 2 * p + (kcl >> 1);   // compile-time after unroll
            #pragma unroll
            for (int et = 0; et < 4; et++) {
                _Float16 s = eav[et][k >> 3][k & 7];
                h8v es = {s, s, s, s, s, s, s, s};
                h8v zf = es * ((kcl & 1) ? xf1[et] : xf0[et]);
                #pragma unroll
                for (int ct = 0; ct < 2; ct++)
                    acc[et][ct] = __builtin_amdgcn_mfma_f32_16x16x32_f16(af[ct], zf, acc[et][ct], 0, 0, 0);
            }
        }
    }
    // bias block: kc = 32,33 ; z = x fragment; A-frags direct from L2 (hot)
    #pragma unroll
    for (int kcl = 0; kcl < 2; kcl++) {
        int kc = 32 + kcl;
        h8v af[2];
        #pragma unroll
        for (int ct = 0; ct < 2; ct++)
            af[ct] = *(const h8v*)(wfh + (size_t)(kc * 4 + ctH * 2 + ct) * 512 + l * 8);
        #pragma unroll
        for (int et = 0; et < 4; et++) {
            h8v zf = (kcl & 1) ? xf1[et] : xf0[et];
            #pragma unroll
            for (int ct = 0; ct < 2; ct++)
                acc[et][ct] = __builtin_amdgcn_mfma_f32_16x16x32_f16(af[ct], zf, acc[et][ct], 0, 0, 0);
        }
    }

    #pragma unroll
    for (int et = 0; et < 4; et++) {
        int e = eact[et];
        if (e < E) {
            u16* mr = msg + (size_t)e * 64 + g * 4;
            #pragma unroll
            for (int ct = 0; ct < 2; ct++) {
                ushort4 pk;
                pk.x = f2h(acc[et][ct][0]);
                pk.y = f2h(acc[et][ct][1]);
                pk.z = f2h(acc[et][ct][2]);
                pk.w = f2h(acc[et][ct][3]);
                *(ushort4*)(mr + (ctH * 2 + ct) * 16) = pk;
            }
        }
    }
}

// ---- C (fused gather + C1 + C2, MFMA fp16, single barrier) — R17 base.
// NEW (only change): gather prefetches the first 4 edge ids with ONE int4
// load (tab rows are 128 B padded -> always-safe read), then issues the <=4
// msg-row loads as independent predicated accesses -> breaks the serial
// tab[j] -> msg dependent-load chain (was ~2 x 200 cy per edge). Tail loop
// handles deg>4 (P ~ 5%).
__global__ __launch_bounds__(256) void k_C(
        const float* __restrict__ x, const u16* __restrict__ msg,
        const int* __restrict__ deg, const int* __restrict__ tab,
        const u16* __restrict__ w1, const u16* __restrict__ w2,
        const float* __restrict__ conv_b, const float* __restrict__ b_hh,
        const float* __restrict__ b_ih, float* __restrict__ hout, int N) {
    __shared__ float mld[4][16][68];
    int t = threadIdx.x, l = t & 63, w = t >> 6, g = l >> 4;
    int n0 = blockIdx.x * 64 + w * 16;
    int node = n0 + (l & 15);
    int nc = node < N ? node : N - 1;
    const float* xrow = x + (size_t)nc * 64 + g * 8;
    const _Float16* w1h = (const _Float16*)w1;
    const _Float16* w2h = (const _Float16*)w2;

    h8v xh[2];
    #pragma unroll
    for (int kc = 0; kc < 2; kc++) {
        f32x4 a = *(const f32x4*)(xrow + kc * 32);
        f32x4 b = *(const f32x4*)(xrow + kc * 32 + 4);
        #pragma unroll
        for (int j = 0; j < 8; j++) xh[kc][j] = (_Float16)(j < 4 ? a[j] : b[j - 4]);
    }

    // padded-table gather of in-edge messages (chain-broken prefetch)
    f32x4 avs[4];
    #pragma unroll
    for (int ct = 0; ct < 4; ct++) avs[ct] = (f32x4)(0.f);
    if (node < N) {
        int dg = deg[node];
        dg = dg < CAP ? dg : CAP;
        const int* tr = tab + (size_t)node * CAP;
        int4 ev = *(const int4*)(tr);        // 16B prefetch of ids 0..3 (safe: padded)
        int eids[4] = {ev.x, ev.y, ev.z, ev.w};
        #pragma unroll
        for (int j = 0; j < 4; j++) {
            if (j < dg) {
                const u16* mr = msg + (size_t)eids[j] * 64 + g * 4;
                #pragma unroll
                for (int ct = 0; ct < 4; ct++) {
                    ushort4 mv = *(const ushort4*)(mr + ct * 16);
                    avs[ct][0] += h2f(mv.x);
                    avs[ct][1] += h2f(mv.y);
                    avs[ct][2] += h2f(mv.z);
                    avs[ct][3] += h2f(mv.w);
                }
            }
        }
        for (int j = 4; j < dg; j++) {        // rare tail (P(deg>4) ~ 5%)
            int eid = tr[j];
            const u16* mr = msg + (size_t)eid * 64 + g * 4;
            #pragma unroll
            for (int ct = 0; ct < 4; ct++) {
                ushort4 mv = *(const ushort4*)(mr + ct * 16);
                avs[ct][0] += h2f(mv.x);
                avs[ct][1] += h2f(mv.y);
                avs[ct][2] += h2f(mv.z);
                avs[ct][3] += h2f(mv.w);
            }
        }
    }

    // phase1: A-frags direct from L2 (28 KB shared chip-wide, L2-hot)
    f32x4 acc1[16];
    #pragma unroll
    for (int ct = 0; ct < 16; ct++) acc1[ct] = (f32x4)(0.f);
    #pragma unroll
    for (int kc = 0; kc < 2; kc++) {
        #pragma unroll
        for (int ct = 0; ct < 16; ct++) {
            h8v wh = *(const h8v*)(w1h + (size_t)(kc * 16 + ct) * 512 + l * 8);
            acc1[ct] = __builtin_amdgcn_mfma_f32_16x16x32_f16(wh, xh[kc], acc1[ct], 0, 0, 0);
        }
    }

    // epilogue 1: m -> LDS (16x64 lane transpose); gh = acc1[4..15]+b_hh
    #pragma unroll
    for (int ct = 0; ct < 4; ct++) {
        int c = ct * 16 + g * 4;
        f32x4 cb = *(const f32x4*)(conv_b + c);
        f32x4 mv;
        #pragma unroll
        for (int r = 0; r < 4; r++) mv[r] = fmaxf(acc1[ct][r] + avs[ct][r] + cb[r], 0.f);
        *(f32x4*)(&mld[w][l & 15][c]) = mv;
    }
    #pragma unroll
    for (int ct = 4; ct < 16; ct++) {
        int c = (ct - 4) * 16 + g * 4;
        f32x4 bh = *(const f32x4*)(b_hh + c);
        #pragma unroll
        for (int r = 0; r < 4; r++) acc1[ct][r] += bh[r];
    }
    __syncthreads();   // fence for the cross-lane LDS transpose (R9 lesson)

    h8v mh[2];
    #pragma unroll
    for (int kc = 0; kc < 2; kc++) {
        const float* mr = &mld[w][l & 15][kc * 32 + g * 8];
        f32x4 a = *(const f32x4*)(mr);
        f32x4 b = *(const f32x4*)(mr + 4);
        #pragma unroll
        for (int j = 0; j < 8; j++) mh[kc][j] = (_Float16)(j < 4 ? a[j] : b[j - 4]);
    }

    // phase2
    f32x4 acc2[12];
    #pragma unroll
    for (int ct = 0; ct < 12; ct++) acc2[ct] = (f32x4)(0.f);
    #pragma unroll
    for (int kc = 0; kc < 2; kc++) {
        #pragma unroll
        for (int ct = 0; ct < 12; ct++) {
            h8v wh = *(const h8v*)(w2h + (size_t)(kc * 12 + ct) * 512 + l * 8);
            acc2[ct] = __builtin_amdgcn_mfma_f32_16x16x32_f16(wh, mh[kc], acc2[ct], 0, 0, 0);
        }
    }

    // epilogue 2: gates (all lane-local)
    #pragma unroll
    for (int q = 0; q < 4; q++) {
        int c = q * 16 + g * 4;
        f32x4 bir = *(const f32x4*)(b_ih + c);
        f32x4 biz = *(const f32x4*)(b_ih + 64 + c);
        f32x4 bin = *(const f32x4*)(b_ih + 128 + c);
        f32x4 hv = (f32x4)(0.f);
        if (node < N) hv = *(const f32x4*)(x + (size_t)node * 64 + c);
        f32x4 outv;
        #pragma unroll
        for (int r = 0; r < 4; r++) {
            float rr = sigm(acc2[q][r] + bir[r] + acc1[4 + q][r]);
            float zz = sigm(acc2[4 + q][r] + biz[r] + acc1[8 + q][r]);
            float nt = tanh_f(acc2[8 + q][r] + bin[r] + rr * acc1[12 + q][r]);
            outv[r] = (1.f - zz) * nt + zz * hv[r];
        }
        if (node < N) *(f32x4*)(hout + (size_t)node * 64 + c) = outv;
    }
}

extern "C" void kernel_launch(void* const* d_in, const int* in_sizes, int n_in,
                              void* d_out, int out_size, void* d_ws, size_t ws_size,
                              hipStream_t stream) {
    const float* x_in   = (const float*)d_in[0];
    const int*   ei     = (const int*)d_in[1];
    const float* ea     = (const float*)d_in[2];
    const float* lin0_w = (const float*)d_in[3];
    const float* lin0_b = (const float*)d_in[4];
    const float* nn_w   = (const float*)d_in[5];
    const float* nn_b   = (const float*)d_in[6];
    const float* root   = (const float*)d_in[7];
    const float* conv_b = (const float*)d_in[8];
    const float* w_ih   = (const float*)d_in[9];
    const float* w_hh   = (const float*)d_in[10];
    const float* b_ih   = (const float*)d_in[11];
    const float* b_hh   = (const float*)d_in[12];

    int N = in_sizes[0] / 32;
    int E = in_sizes[1] / 2;

    char* ws = (char*)d_ws;
    size_t off = 0;
    auto alloc = [&](size_t bytes) { char* p = ws + off; off += (bytes + 255) & ~(size_t)255; return p; };
    float* xbuf   = (float*)alloc((size_t)N * 64 * 4);
    u16*   msg    = (u16*)alloc((size_t)E * 64 * 2);
    u16*   wf2    = (u16*)alloc((size_t)34 * 4 * 512 * 2);
    u16*   ea16   = (u16*)alloc((size_t)E * 16 * 2);
    u16*   w1     = (u16*)alloc(16384 * 2);
    u16*   w2     = (u16*)alloc(12288 * 2);
    u16*   w0     = (u16*)alloc(2048 * 2);
    int*   deg    = (int*)alloc((size_t)N * 4);
    int*   tab    = (int*)alloc((size_t)N * CAP * 4);
    (void)ws_size;

    int nEA = E * 16;
    int nbuild = (E + 255) / 256;
    int ntile  = (N + 63) / 64;

    hipLaunchKernelGGL(k_prep, dim3((nEA + 255) / 256), dim3(256), 0, stream,
                       nn_w, nn_b, root, w_hh, w_ih, lin0_w, ea,
                       wf2, w1, w2, w0, ea16, deg, N, nEA);
    hipLaunchKernelGGL(k_pre2, dim3(nbuild + ntile), dim3(256), 0, stream,
                       ei, deg, tab, x_in, w0, lin0_b, xbuf, N, E);

    for (int it = 0; it < 3; it++) {
        hipLaunchKernelGGL(k_AB, dim3((E + 255) / 256, 2), dim3(256), 0, stream,
                           xbuf, ea16, wf2, ei, msg, E);
        float* hout = (it == 2) ? (float*)d_out : xbuf;
        hipLaunchKernelGGL(k_C, dim3(ntile), dim3(256), 0, stream, xbuf, msg,
                           deg, tab, w1, w2, conv_b, b_hh, b_ih, hout, N);
    }
}